// Round 1
// baseline (1632.357 us; speedup 1.0000x reference)
//
#include <hip/hip_runtime.h>
#include <hip/hip_bf16.h>
#include <math.h>

#define WEPS 1e-5f
#define WSCALE 0.125f

enum { EPI_NONE=0, EPI_BIAS=1, EPI_BN_RELU=2, EPI_ACC=3 };

// ---------------- generic fp32 GEMM ----------------
// C[M,N] = A[M,K] @ B[K,N] (+epilogue). BM=BN=128, BK=16, 256 threads, 8x8/thread.
// M multiple of 128, K multiple of 16, N multiple of 64 (col-guarded).
template<int EPI>
__launch_bounds__(256)
__global__ void gemm_f32(const float* __restrict__ A, int lda,
                         const float* __restrict__ B, int ldb,
                         float* __restrict__ C, int ldc,
                         int N, int K,
                         const float* __restrict__ bias,
                         const float* __restrict__ bn_g,
                         const float* __restrict__ bn_b)
{
    __shared__ float As[16][132];
    __shared__ float Bs[16][132];
    const int bm = blockIdx.y << 7;
    const int bn = blockIdx.x << 7;
    const int tid = threadIdx.x;
    const int tx = tid & 15, ty = tid >> 4;
    float acc[8][8] = {};
    for (int k0 = 0; k0 < K; k0 += 16) {
        #pragma unroll
        for (int i = 0; i < 2; i++) {            // A tile 128x16, float4 along K
            int idx = tid + (i << 8);            // 0..511
            int m  = idx >> 2;
            int c4 = (idx & 3) << 2;
            float4 v = *(const float4*)(A + (bm + m) * lda + k0 + c4);
            As[c4+0][m] = v.x; As[c4+1][m] = v.y; As[c4+2][m] = v.z; As[c4+3][m] = v.w;
        }
        #pragma unroll
        for (int i = 0; i < 2; i++) {            // B tile 16x128, float4 along N
            int idx = tid + (i << 8);
            int kk = idx >> 5;
            int n4 = (idx & 31) << 2;
            int col = bn + n4;
            float4 v = make_float4(0.f,0.f,0.f,0.f);
            if (col < N) v = *(const float4*)(B + (k0 + kk) * ldb + col);
            *(float4*)&Bs[kk][n4] = v;
        }
        __syncthreads();
        #pragma unroll
        for (int kk = 0; kk < 16; kk++) {
            float a0[8], b0[8];
            #pragma unroll
            for (int i = 0; i < 8; i++) a0[i] = As[kk][(ty<<3)+i];
            #pragma unroll
            for (int j = 0; j < 8; j++) b0[j] = Bs[kk][(tx<<3)+j];
            #pragma unroll
            for (int i = 0; i < 8; i++)
                #pragma unroll
                for (int j = 0; j < 8; j++)
                    acc[i][j] = fmaf(a0[i], b0[j], acc[i][j]);
        }
        __syncthreads();
    }
    const float bn_s = 0.99999500003749968f;      // 1/sqrt(1+1e-5)
    #pragma unroll
    for (int i = 0; i < 8; i++) {
        int row = bm + (ty<<3) + i;
        #pragma unroll
        for (int j4 = 0; j4 < 2; j4++) {
            int col = bn + (tx<<3) + (j4<<2);
            if (col >= N) continue;
            float v[4];
            #pragma unroll
            for (int j = 0; j < 4; j++) {
                float t = acc[i][(j4<<2)+j];
                int c = col + j;
                if (EPI == EPI_BIAS) t += bias[c];
                if (EPI == EPI_BN_RELU) {
                    float s = bn_g[c] * bn_s;
                    t = fmaxf((t + bias[c]) * s + bn_b[c], 0.f);
                }
                v[j] = t;
            }
            float* cp = C + row * ldc + col;
            if (EPI == EPI_ACC) {
                float4 old = *(const float4*)cp;
                v[0]+=old.x; v[1]+=old.y; v[2]+=old.z; v[3]+=old.w;
            }
            *(float4*)cp = make_float4(v[0],v[1],v[2],v[3]);
        }
    }
}

// ---------------- 3x3 conv as implicit-im2col GEMM ----------------
// Xd: (B*1024, 256) channel-last over 32x32 spatial. Bt: (2304, 256) = W[tap*256+i][o].
// M=4096, N=256, K=2304. Out xd2 (B*1024, 256) + BN + ReLU.
__launch_bounds__(256)
__global__ void conv3_gemm(const float* __restrict__ Xd,
                           const float* __restrict__ Bt,
                           float* __restrict__ C,
                           const float* __restrict__ bias,
                           const float* __restrict__ bn_g,
                           const float* __restrict__ bn_b)
{
    __shared__ float As[16][132];
    __shared__ float Bs[16][132];
    const int bm = blockIdx.y << 7;
    const int bn = blockIdx.x << 7;
    const int tid = threadIdx.x;
    const int tx = tid & 15, ty = tid >> 4;
    float acc[8][8] = {};
    for (int k0 = 0; k0 < 2304; k0 += 16) {
        int tap = k0 >> 8;                 // constant within tile (256 % 16 == 0)
        int dy = tap / 3 - 1;
        int dx = tap - (tap / 3) * 3 - 1;
        int i0 = k0 & 255;
        #pragma unroll
        for (int i = 0; i < 2; i++) {
            int idx = tid + (i << 8);
            int m  = idx >> 2;
            int c4 = (idx & 3) << 2;
            int row = bm + m;
            int b = row >> 10, s = row & 1023;
            int y = (s >> 5) + dy, x = (s & 31) + dx;
            float4 v = make_float4(0.f,0.f,0.f,0.f);
            if ((unsigned)y < 32u && (unsigned)x < 32u)
                v = *(const float4*)(Xd + ((((b<<10) + (y<<5) + x) << 8) + i0 + c4));
            As[c4+0][m] = v.x; As[c4+1][m] = v.y; As[c4+2][m] = v.z; As[c4+3][m] = v.w;
        }
        #pragma unroll
        for (int i = 0; i < 2; i++) {
            int idx = tid + (i << 8);
            int kk = idx >> 5;
            int n4 = (idx & 31) << 2;
            float4 v = *(const float4*)(Bt + (k0 + kk) * 256 + bn + n4);
            *(float4*)&Bs[kk][n4] = v;
        }
        __syncthreads();
        #pragma unroll
        for (int kk = 0; kk < 16; kk++) {
            float a0[8], b0[8];
            #pragma unroll
            for (int i = 0; i < 8; i++) a0[i] = As[kk][(ty<<3)+i];
            #pragma unroll
            for (int j = 0; j < 8; j++) b0[j] = Bs[kk][(tx<<3)+j];
            #pragma unroll
            for (int i = 0; i < 8; i++)
                #pragma unroll
                for (int j = 0; j < 8; j++)
                    acc[i][j] = fmaf(a0[i], b0[j], acc[i][j]);
        }
        __syncthreads();
    }
    const float bn_s = 0.99999500003749968f;
    #pragma unroll
    for (int i = 0; i < 8; i++) {
        int row = bm + (ty<<3) + i;
        #pragma unroll
        for (int j4 = 0; j4 < 2; j4++) {
            int col = bn + (tx<<3) + (j4<<2);
            float v[4];
            #pragma unroll
            for (int j = 0; j < 4; j++) {
                int c = col + j;
                float s = bn_g[c] * bn_s;
                v[j] = fmaxf((acc[i][(j4<<2)+j] + bias[c]) * s + bn_b[c], 0.f);
            }
            *(float4*)(C + row * 256 + col) = make_float4(v[0],v[1],v[2],v[3]);
        }
    }
}

// ---------------- filter weight transpose: Wt[tap*256+i][o] = Wf[o][i][tap] ----------------
__global__ void wt_kernel(const float* __restrict__ Wf, float* __restrict__ Wt)
{
    int k = blockIdx.x;      // 0..2303
    int o = threadIdx.x;     // 0..255
    int i = k & 255, tap = k >> 8;
    Wt[k * 256 + o] = Wf[(o * 256 + i) * 9 + tap];
}

// ---------------- window attention: one wave per (b, window, head) ----------------
// qkv: (B*4096, 768) rows in token order; sa_o: (B*4096, 256)
__launch_bounds__(256)
__global__ void win_attn(const float* __restrict__ qkv, float* __restrict__ sa_o)
{
    int gw = blockIdx.x * 4 + (threadIdx.x >> 6);   // 0..16383
    int lane = threadIdx.x & 63;                    // = d
    int b  = gw >> 12;
    int g  = (gw >> 2) & 1023;
    int sh = gw & 3;
    int hg = g >> 5, wg = g & 31;
    float q[4], k[4], v[4];
    int rows[4];
    #pragma unroll
    for (int l = 0; l < 4; l++) {
        int h = (hg << 1) + (l >> 1), w = (wg << 1) + (l & 1);
        int row = (b << 12) + (h << 6) + w;
        rows[l] = row;
        const float* p = qkv + row * 768 + sh * 64 + lane;
        q[l] = p[0]; k[l] = p[256]; v[l] = p[512];
    }
    float s[4][4];
    #pragma unroll
    for (int l = 0; l < 4; l++)
        #pragma unroll
        for (int m = 0; m < 4; m++) s[l][m] = q[l] * k[m];
    #pragma unroll
    for (int off = 32; off > 0; off >>= 1)
        #pragma unroll
        for (int l = 0; l < 4; l++)
            #pragma unroll
            for (int m = 0; m < 4; m++)
                s[l][m] += __shfl_xor(s[l][m], off, 64);
    #pragma unroll
    for (int l = 0; l < 4; l++) {
        float s0 = s[l][0]*WSCALE, s1 = s[l][1]*WSCALE, s2 = s[l][2]*WSCALE, s3 = s[l][3]*WSCALE;
        float mx = fmaxf(fmaxf(s0,s1), fmaxf(s2,s3));
        float p0 = __expf(s0-mx), p1 = __expf(s1-mx), p2 = __expf(s2-mx), p3 = __expf(s3-mx);
        float inv = 1.f / (p0+p1+p2+p3);
        float o = (p0*v[0] + p1*v[1] + p2*v[2] + p3*v[3]) * inv;
        sa_o[rows[l] * 256 + sh * 64 + lane] = o;
    }
}

// ---------------- Haar DWT: r (B*4096, 64) -> xd (B*1024, 256) channel-last ----------------
__global__ void dwt_kernel(const float* __restrict__ r, float* __restrict__ xd)
{
    int t = blockIdx.x * 256 + threadIdx.x;  // 262144
    int o = t & 63;
    int x = (t >> 6) & 31;
    int y = (t >> 11) & 31;
    int b = t >> 16;
    const float* rb = r + (b << 18);
    int base = (y << 7) * 64 / 64 * 64;      // (2y)*64 computed below explicitly
    base = ((y << 1) << 6) + (x << 1);       // row (2y), col (2x)
    float a  = rb[(base     ) * 64 + o];
    float bb = rb[(base +  1) * 64 + o];
    float c  = rb[(base + 64) * 64 + o];
    float d  = rb[(base + 65) * 64 + o];
    float ll = 0.5f*(a+bb+c+d), lh = 0.5f*(a+bb-c-d);
    float hl = 0.5f*(a-bb+c-d), hh = 0.5f*(a-bb-c+d);
    float* outp = xd + (((b << 10) + (y << 5) + x) << 8) + o;
    outp[0]   = ll; outp[64]  = lh; outp[128] = hl; outp[192] = hh;
}

// ---------------- Haar IDWT: xd2 (B*1024, 256) -> x_idwt (B*4096, 64) ----------------
__global__ void idwt_kernel(const float* __restrict__ xd, float* __restrict__ xi)
{
    int t = blockIdx.x * 256 + threadIdx.x;
    int o = t & 63;
    int x = (t >> 6) & 31;
    int y = (t >> 11) & 31;
    int b = t >> 16;
    const float* p = xd + (((b << 10) + (y << 5) + x) << 8);
    float ll = p[o], lh = p[64+o], hl = p[128+o], hh = p[192+o];
    float y00 = 0.5f*(ll+lh+hl+hh);
    float y01 = 0.5f*(ll+lh-hl-hh);
    float y10 = 0.5f*(ll-lh+hl-hh);
    float y11 = 0.5f*(ll-lh-hl+hh);
    float* ob = xi + (b << 18);
    int base = ((y << 1) << 6) + (x << 1);
    ob[(base     ) * 64 + o] = y00;
    ob[(base +  1) * 64 + o] = y01;
    ob[(base + 64) * 64 + o] = y10;
    ob[(base + 65) * 64 + o] = y11;
}

// ---------------- LayerNorm over 256, one block per row ----------------
__launch_bounds__(256)
__global__ void ln_kernel(const float* __restrict__ X, const float* __restrict__ g,
                          const float* __restrict__ bta, float* __restrict__ Y)
{
    int row = blockIdx.x;
    int t = threadIdx.x;
    float x = X[row * 256 + t];
    __shared__ float red[4];
    int wv = t >> 6, ln = t & 63;
    float s = x;
    #pragma unroll
    for (int off = 32; off > 0; off >>= 1) s += __shfl_xor(s, off, 64);
    if (ln == 0) red[wv] = s;
    __syncthreads();
    float m = (red[0]+red[1]+red[2]+red[3]) * (1.f/256.f);
    float d = x - m;
    float s2 = d * d;
    #pragma unroll
    for (int off = 32; off > 0; off >>= 1) s2 += __shfl_xor(s2, off, 64);
    __syncthreads();
    if (ln == 0) red[wv] = s2;
    __syncthreads();
    float var = (red[0]+red[1]+red[2]+red[3]) * (1.f/256.f);
    float inv = 1.f / sqrtf(var + WEPS);
    Y[row * 256 + t] = d * inv * g[t] + bta[t];
}

// ---------------- flash attention: per-thread query, online softmax ----------------
// qw: (B*4096, 256) col = wh*64+d;  kv: (B*1024, 512) k at wh*64+d, v at 256+wh*64+d
// ow: (B*4096, 256) col = wh*64+d
__launch_bounds__(256, 1)
__global__ void flash_attn(const float* __restrict__ qw, const float* __restrict__ kv,
                           float* __restrict__ ow)
{
    int bh = blockIdx.y;             // b*4 + wh
    int b = bh >> 2, wh = bh & 3;
    int tid = threadIdx.x;
    int qn = blockIdx.x * 256 + tid; // 0..4095
    int qrow = (b << 12) + qn;
    const float4* qp = (const float4*)(qw + qrow * 256 + wh * 64);
    float q[64];
    #pragma unroll
    for (int i = 0; i < 16; i++) {
        float4 t4 = qp[i];
        q[4*i] = t4.x; q[4*i+1] = t4.y; q[4*i+2] = t4.z; q[4*i+3] = t4.w;
    }
    float acc[64] = {};
    float mmax = -1e30f, lsum = 0.f;
    __shared__ float Ks[64][64];
    __shared__ float Vs[64][64];
    const float* kvb = kv + ((size_t)(b << 10)) * 512;
    for (int t0 = 0; t0 < 1024; t0 += 64) {
        __syncthreads();
        #pragma unroll
        for (int i = 0; i < 4; i++) {
            int e = tid + (i << 8);          // 0..1023
            int j = e >> 4;
            int d4 = (e & 15) << 2;
            const float* src = kvb + (t0 + j) * 512 + wh * 64;
            *(float4*)&Ks[j][d4] = *(const float4*)(src + d4);
            *(float4*)&Vs[j][d4] = *(const float4*)(src + 256 + d4);
        }
        __syncthreads();
        for (int j = 0; j < 64; j++) {
            float s = 0.f;
            #pragma unroll
            for (int d = 0; d < 64; d++) s = fmaf(q[d], Ks[j][d], s);
            s *= WSCALE;
            if (s > mmax) {
                float corr = __expf(mmax - s);
                lsum *= corr;
                #pragma unroll
                for (int d = 0; d < 64; d++) acc[d] *= corr;
                mmax = s;
            }
            float p = __expf(s - mmax);
            lsum += p;
            #pragma unroll
            for (int d = 0; d < 64; d++) acc[d] = fmaf(p, Vs[j][d], acc[d]);
        }
    }
    float inv = 1.f / lsum;
    float* op = ow + qrow * 256 + wh * 64;
    #pragma unroll
    for (int i = 0; i < 16; i++) {
        float4 t4 = make_float4(acc[4*i]*inv, acc[4*i+1]*inv, acc[4*i+2]*inv, acc[4*i+3]*inv);
        *(float4*)(op + 4*i) = t4;
    }
}

extern "C" void kernel_launch(void* const* d_in, const int* in_sizes, int n_in,
                              void* d_out, int out_size, void* d_ws, size_t ws_size,
                              hipStream_t stream)
{
    const float* x        = (const float*)d_in[0];
    const float* wq_w     = (const float*)d_in[1];
    const float* kv_ln_g  = (const float*)d_in[2];
    const float* kv_ln_b  = (const float*)d_in[3];
    const float* wkv_w    = (const float*)d_in[4];
    const float* wkv_b    = (const float*)d_in[5];
    const float* wproj_w  = (const float*)d_in[6];
    const float* wproj_b  = (const float*)d_in[7];
    const float* reduce_w = (const float*)d_in[8];
    const float* reduce_b = (const float*)d_in[9];
    const float* rbn_g    = (const float*)d_in[10];
    const float* rbn_b    = (const float*)d_in[11];
    const float* filter_w = (const float*)d_in[12];
    const float* filter_b = (const float*)d_in[13];
    const float* fbn_g    = (const float*)d_in[14];
    const float* fbn_b    = (const float*)d_in[15];
    const float* sqkv_w   = (const float*)d_in[16];
    const float* sproj_w  = (const float*)d_in[17];
    const float* sproj_b  = (const float*)d_in[18];
    float* out = (float*)d_out;
    float* ws  = (float*)d_ws;

    // workspace layout (floats); ow reuses qkv, wt reuses sa_o
    float* qkv   = ws + 0;          // 12582912
    float* ow    = ws + 0;          // reuse (qkv dead after win_attn)
    float* sa_o  = ws + 12582912;   // 4194304
    float* wt    = ws + 12582912;   // reuse (sa_o dead after sproj)
    float* qw    = ws + 16777216;   // 4194304
    float* rbuf  = ws + 20971520;   // 1048576
    float* xd1   = ws + 22020096;   // 1048576
    float* xd2   = ws + 23068672;   // 1048576
    float* kvin  = ws + 24117248;   // 1048576
    float* kvb   = ws + 25165824;   // 2097152
    float* xidwt = ws + 27262976;   // 1048576  (total 28311552 floats = 113.2 MB)

    dim3 blk(256);

    // 1. qkv = x @ sqkv_w            (M=16384, N=768, K=512)
    gemm_f32<EPI_NONE><<<dim3(6,128), blk, 0, stream>>>(x, 512, sqkv_w, 768, qkv, 768,
                                                        768, 512, nullptr, nullptr, nullptr);
    // 2. 2x2 window attention -> sa_o
    win_attn<<<dim3(4096), blk, 0, stream>>>(qkv, sa_o);
    // 3. sa_out = sa_o @ sproj_w + b -> out cols [0,256)
    gemm_f32<EPI_BIAS><<<dim3(2,128), blk, 0, stream>>>(sa_o, 256, sproj_w, 256, out, 512,
                                                        256, 256, sproj_b, nullptr, nullptr);
    // 4. qw = x @ wq_w               (M=16384, N=256, K=512)
    gemm_f32<EPI_NONE><<<dim3(2,128), blk, 0, stream>>>(x, 512, wq_w, 256, qw, 256,
                                                        256, 512, nullptr, nullptr, nullptr);
    // 5. r = relu(bn(x @ reduce_w + reduce_b))   (N=64)
    gemm_f32<EPI_BN_RELU><<<dim3(1,128), blk, 0, stream>>>(x, 512, reduce_w, 64, rbuf, 64,
                                                           64, 512, reduce_b, rbn_g, rbn_b);
    // 6. transpose conv weights
    wt_kernel<<<dim3(2304), blk, 0, stream>>>(filter_w, wt);
    // 7. DWT
    dwt_kernel<<<dim3(1024), blk, 0, stream>>>(rbuf, xd1);
    // 8. 3x3 conv + BN + ReLU        (M=4096, N=256, K=2304)
    conv3_gemm<<<dim3(2,32), blk, 0, stream>>>(xd1, wt, xd2, filter_b, fbn_g, fbn_b);
    // 9. layernorm -> kvin
    ln_kernel<<<dim3(4096), blk, 0, stream>>>(xd2, kv_ln_g, kv_ln_b, kvin);
    // 10. kv = kvin @ wkv_w + b      (M=4096, N=512, K=256)
    gemm_f32<EPI_BIAS><<<dim3(4,32), blk, 0, stream>>>(kvin, 256, wkv_w, 512, kvb, 512,
                                                       512, 256, wkv_b, nullptr, nullptr);
    // 11. IDWT -> x_idwt
    idwt_kernel<<<dim3(1024), blk, 0, stream>>>(xd2, xidwt);
    // 12. flash attention -> ow
    flash_attn<<<dim3(16,16), blk, 0, stream>>>(qw, kvb, ow);
    // 13. wa = ow @ wproj_w[0:256] + b -> out cols [256,512)
    gemm_f32<EPI_BIAS><<<dim3(2,128), blk, 0, stream>>>(ow, 256, wproj_w, 256, out + 256, 512,
                                                        256, 256, wproj_b, nullptr, nullptr);
    // 14. wa += x_idwt @ wproj_w[256:320]
    gemm_f32<EPI_ACC><<<dim3(2,128), blk, 0, stream>>>(xidwt, 64, wproj_w + 256*256, 256,
                                                       out + 256, 512, 256, 64,
                                                       nullptr, nullptr, nullptr);
}

// Round 2
// 872.150 us; speedup vs baseline: 1.8716x; 1.8716x over previous
//
#include <hip/hip_runtime.h>
#include <hip/hip_bf16.h>
#include <math.h>

#define WEPS 1e-5f
#define WSCALE 0.125f

enum { EPI_NONE=0, EPI_BIAS=1, EPI_BN_RELU=2, EPI_ACC=3 };

typedef __attribute__((ext_vector_type(8))) short bf16x8;
typedef __attribute__((ext_vector_type(4))) float f32x4;
typedef __attribute__((ext_vector_type(8))) unsigned short ushort8;

static __device__ inline unsigned short f2bf(float f) {
    __hip_bfloat16 h = __float2bfloat16(f);
    return *(unsigned short*)&h;
}
static __device__ inline unsigned pack2bf(float a, float b) {
    return (unsigned)f2bf(a) | ((unsigned)f2bf(b) << 16);
}

// ---------------- generic fp32 GEMM ----------------
// C[M,N] = A[M,K] @ B[K,N] (+epilogue). BM=BN=128, BK=16, 256 threads, 8x8/thread.
template<int EPI, int OBF16>
__launch_bounds__(256)
__global__ void gemm_f32(const float* __restrict__ A, int lda,
                         const float* __restrict__ B, int ldb,
                         void* __restrict__ Cv, int ldc,
                         int N, int K,
                         const float* __restrict__ bias,
                         const float* __restrict__ bn_g,
                         const float* __restrict__ bn_b)
{
    __shared__ float As[16][132];
    __shared__ float Bs[16][132];
    const int bm = blockIdx.y << 7;
    const int bn = blockIdx.x << 7;
    const int tid = threadIdx.x;
    const int tx = tid & 15, ty = tid >> 4;
    float acc[8][8] = {};
    for (int k0 = 0; k0 < K; k0 += 16) {
        #pragma unroll
        for (int i = 0; i < 2; i++) {
            int idx = tid + (i << 8);
            int m  = idx >> 2;
            int c4 = (idx & 3) << 2;
            float4 v = *(const float4*)(A + (bm + m) * lda + k0 + c4);
            As[c4+0][m] = v.x; As[c4+1][m] = v.y; As[c4+2][m] = v.z; As[c4+3][m] = v.w;
        }
        #pragma unroll
        for (int i = 0; i < 2; i++) {
            int idx = tid + (i << 8);
            int kk = idx >> 5;
            int n4 = (idx & 31) << 2;
            int col = bn + n4;
            float4 v = make_float4(0.f,0.f,0.f,0.f);
            if (col < N) v = *(const float4*)(B + (k0 + kk) * ldb + col);
            *(float4*)&Bs[kk][n4] = v;
        }
        __syncthreads();
        #pragma unroll
        for (int kk = 0; kk < 16; kk++) {
            float a0[8], b0[8];
            #pragma unroll
            for (int i = 0; i < 8; i++) a0[i] = As[kk][(ty<<3)+i];
            #pragma unroll
            for (int j = 0; j < 8; j++) b0[j] = Bs[kk][(tx<<3)+j];
            #pragma unroll
            for (int i = 0; i < 8; i++)
                #pragma unroll
                for (int j = 0; j < 8; j++)
                    acc[i][j] = fmaf(a0[i], b0[j], acc[i][j]);
        }
        __syncthreads();
    }
    const float bn_s = 0.99999500003749968f;
    if (OBF16) {
        __hip_bfloat16* C = (__hip_bfloat16*)Cv;
        #pragma unroll
        for (int i = 0; i < 8; i++) {
            int row = bm + (ty<<3) + i;
            int col0 = bn + (tx<<3);
            ushort8 h;
            #pragma unroll
            for (int j = 0; j < 8; j++) {
                float t = acc[i][j];
                if (EPI == EPI_BIAS) t += bias[col0 + j];
                h[j] = f2bf(t);
            }
            *(ushort8*)(C + (size_t)row * ldc + col0) = h;
        }
        return;
    }
    float* C = (float*)Cv;
    #pragma unroll
    for (int i = 0; i < 8; i++) {
        int row = bm + (ty<<3) + i;
        #pragma unroll
        for (int j4 = 0; j4 < 2; j4++) {
            int col = bn + (tx<<3) + (j4<<2);
            if (col >= N) continue;
            float v[4];
            #pragma unroll
            for (int j = 0; j < 4; j++) {
                float t = acc[i][(j4<<2)+j];
                int c = col + j;
                if (EPI == EPI_BIAS) t += bias[c];
                if (EPI == EPI_BN_RELU) {
                    float s = bn_g[c] * bn_s;
                    t = fmaxf((t + bias[c]) * s + bn_b[c], 0.f);
                }
                v[j] = t;
            }
            float* cp = C + row * ldc + col;
            if (EPI == EPI_ACC) {
                float4 old = *(const float4*)cp;
                v[0]+=old.x; v[1]+=old.y; v[2]+=old.z; v[3]+=old.w;
            }
            *(float4*)cp = make_float4(v[0],v[1],v[2],v[3]);
        }
    }
}

// ---------------- kv GEMM: fp32 compute, bf16 K (row-major) + V (transposed) out ----------
// A = kvin (4096x256), B = wkv_w (256x512). cols<256 -> k, cols>=256 -> v (transposed).
__launch_bounds__(256)
__global__ void gemm_kv(const float* __restrict__ A,
                        const float* __restrict__ B,
                        __hip_bfloat16* __restrict__ kbo,   // [16][1024][64]
                        __hip_bfloat16* __restrict__ vto,   // [16][64][1024]
                        const float* __restrict__ bias)
{
    __shared__ float As[16][132];
    __shared__ float Bs[16][132];
    const int bm = blockIdx.y << 7;
    const int bn = blockIdx.x << 7;
    const int tid = threadIdx.x;
    const int tx = tid & 15, ty = tid >> 4;
    float acc[8][8] = {};
    for (int k0 = 0; k0 < 256; k0 += 16) {
        #pragma unroll
        for (int i = 0; i < 2; i++) {
            int idx = tid + (i << 8);
            int m  = idx >> 2;
            int c4 = (idx & 3) << 2;
            float4 v = *(const float4*)(A + (bm + m) * 256 + k0 + c4);
            As[c4+0][m] = v.x; As[c4+1][m] = v.y; As[c4+2][m] = v.z; As[c4+3][m] = v.w;
        }
        #pragma unroll
        for (int i = 0; i < 2; i++) {
            int idx = tid + (i << 8);
            int kk = idx >> 5;
            int n4 = (idx & 31) << 2;
            float4 v = *(const float4*)(B + (k0 + kk) * 512 + bn + n4);
            *(float4*)&Bs[kk][n4] = v;
        }
        __syncthreads();
        #pragma unroll
        for (int kk = 0; kk < 16; kk++) {
            float a0[8], b0[8];
            #pragma unroll
            for (int i = 0; i < 8; i++) a0[i] = As[kk][(ty<<3)+i];
            #pragma unroll
            for (int j = 0; j < 8; j++) b0[j] = Bs[kk][(tx<<3)+j];
            #pragma unroll
            for (int i = 0; i < 8; i++)
                #pragma unroll
                for (int j = 0; j < 8; j++)
                    acc[i][j] = fmaf(a0[i], b0[j], acc[i][j]);
        }
        __syncthreads();
    }
    if (bn < 256) {                 // K part: row-major [bh][token][d]
        #pragma unroll
        for (int i = 0; i < 8; i++) {
            int row = bm + (ty<<3) + i;
            int b = row >> 10, tkn = row & 1023;
            int col0 = bn + (tx<<3);
            int wh = col0 >> 6, d0 = col0 & 63;
            ushort8 h;
            #pragma unroll
            for (int j = 0; j < 8; j++) h[j] = f2bf(acc[i][j] + bias[col0 + j]);
            *(ushort8*)(kbo + (((size_t)((b<<2)+wh)) << 16) + tkn*64 + d0) = h;
        }
    } else {                        // V part: transposed [bh][d][token]
        int row0 = bm + (ty<<3);
        int b = row0 >> 10, tkn0 = row0 & 1023;
        #pragma unroll
        for (int j = 0; j < 8; j++) {
            int c = bn - 256 + (tx<<3) + j;
            int wh = c >> 6, d = c & 63;
            ushort8 h;
            #pragma unroll
            for (int i = 0; i < 8; i++) h[i] = f2bf(acc[i][j] + bias[256 + c]);
            *(ushort8*)(vto + (((size_t)((b<<2)+wh)) << 16) + d*1024 + tkn0) = h;
        }
    }
}

// ---------------- 3x3 conv as implicit-im2col GEMM ----------------
__launch_bounds__(256)
__global__ void conv3_gemm(const float* __restrict__ Xd,
                           const float* __restrict__ Bt,
                           float* __restrict__ C,
                           const float* __restrict__ bias,
                           const float* __restrict__ bn_g,
                           const float* __restrict__ bn_b)
{
    __shared__ float As[16][132];
    __shared__ float Bs[16][132];
    const int bm = blockIdx.y << 7;
    const int bn = blockIdx.x << 7;
    const int tid = threadIdx.x;
    const int tx = tid & 15, ty = tid >> 4;
    float acc[8][8] = {};
    for (int k0 = 0; k0 < 2304; k0 += 16) {
        int tap = k0 >> 8;
        int dy = tap / 3 - 1;
        int dx = tap - (tap / 3) * 3 - 1;
        int i0 = k0 & 255;
        #pragma unroll
        for (int i = 0; i < 2; i++) {
            int idx = tid + (i << 8);
            int m  = idx >> 2;
            int c4 = (idx & 3) << 2;
            int row = bm + m;
            int b = row >> 10, s = row & 1023;
            int y = (s >> 5) + dy, x = (s & 31) + dx;
            float4 v = make_float4(0.f,0.f,0.f,0.f);
            if ((unsigned)y < 32u && (unsigned)x < 32u)
                v = *(const float4*)(Xd + ((((b<<10) + (y<<5) + x) << 8) + i0 + c4));
            As[c4+0][m] = v.x; As[c4+1][m] = v.y; As[c4+2][m] = v.z; As[c4+3][m] = v.w;
        }
        #pragma unroll
        for (int i = 0; i < 2; i++) {
            int idx = tid + (i << 8);
            int kk = idx >> 5;
            int n4 = (idx & 31) << 2;
            float4 v = *(const float4*)(Bt + (k0 + kk) * 256 + bn + n4);
            *(float4*)&Bs[kk][n4] = v;
        }
        __syncthreads();
        #pragma unroll
        for (int kk = 0; kk < 16; kk++) {
            float a0[8], b0[8];
            #pragma unroll
            for (int i = 0; i < 8; i++) a0[i] = As[kk][(ty<<3)+i];
            #pragma unroll
            for (int j = 0; j < 8; j++) b0[j] = Bs[kk][(tx<<3)+j];
            #pragma unroll
            for (int i = 0; i < 8; i++)
                #pragma unroll
                for (int j = 0; j < 8; j++)
                    acc[i][j] = fmaf(a0[i], b0[j], acc[i][j]);
        }
        __syncthreads();
    }
    const float bn_s = 0.99999500003749968f;
    #pragma unroll
    for (int i = 0; i < 8; i++) {
        int row = bm + (ty<<3) + i;
        #pragma unroll
        for (int j4 = 0; j4 < 2; j4++) {
            int col = bn + (tx<<3) + (j4<<2);
            float v[4];
            #pragma unroll
            for (int j = 0; j < 4; j++) {
                int c = col + j;
                float s = bn_g[c] * bn_s;
                v[j] = fmaxf((acc[i][(j4<<2)+j] + bias[c]) * s + bn_b[c], 0.f);
            }
            *(float4*)(C + row * 256 + col) = make_float4(v[0],v[1],v[2],v[3]);
        }
    }
}

// ---------------- filter weight transpose ----------------
__global__ void wt_kernel(const float* __restrict__ Wf, float* __restrict__ Wt)
{
    int k = blockIdx.x;
    int o = threadIdx.x;
    int i = k & 255, tap = k >> 8;
    Wt[k * 256 + o] = Wf[(o * 256 + i) * 9 + tap];
}

// ---------------- window attention ----------------
__launch_bounds__(256)
__global__ void win_attn(const float* __restrict__ qkv, float* __restrict__ sa_o)
{
    int gw = blockIdx.x * 4 + (threadIdx.x >> 6);
    int lane = threadIdx.x & 63;
    int b  = gw >> 12;
    int g  = (gw >> 2) & 1023;
    int sh = gw & 3;
    int hg = g >> 5, wg = g & 31;
    float q[4], k[4], v[4];
    int rows[4];
    #pragma unroll
    for (int l = 0; l < 4; l++) {
        int h = (hg << 1) + (l >> 1), w = (wg << 1) + (l & 1);
        int row = (b << 12) + (h << 6) + w;
        rows[l] = row;
        const float* p = qkv + row * 768 + sh * 64 + lane;
        q[l] = p[0]; k[l] = p[256]; v[l] = p[512];
    }
    float s[4][4];
    #pragma unroll
    for (int l = 0; l < 4; l++)
        #pragma unroll
        for (int m = 0; m < 4; m++) s[l][m] = q[l] * k[m];
    #pragma unroll
    for (int off = 32; off > 0; off >>= 1)
        #pragma unroll
        for (int l = 0; l < 4; l++)
            #pragma unroll
            for (int m = 0; m < 4; m++)
                s[l][m] += __shfl_xor(s[l][m], off, 64);
    #pragma unroll
    for (int l = 0; l < 4; l++) {
        float s0 = s[l][0]*WSCALE, s1 = s[l][1]*WSCALE, s2 = s[l][2]*WSCALE, s3 = s[l][3]*WSCALE;
        float mx = fmaxf(fmaxf(s0,s1), fmaxf(s2,s3));
        float p0 = __expf(s0-mx), p1 = __expf(s1-mx), p2 = __expf(s2-mx), p3 = __expf(s3-mx);
        float inv = 1.f / (p0+p1+p2+p3);
        float o = (p0*v[0] + p1*v[1] + p2*v[2] + p3*v[3]) * inv;
        sa_o[rows[l] * 256 + sh * 64 + lane] = o;
    }
}

// ---------------- Haar DWT ----------------
__global__ void dwt_kernel(const float* __restrict__ r, float* __restrict__ xd)
{
    int t = blockIdx.x * 256 + threadIdx.x;
    int o = t & 63;
    int x = (t >> 6) & 31;
    int y = (t >> 11) & 31;
    int b = t >> 16;
    const float* rb = r + (b << 18);
    int base = ((y << 1) << 6) + (x << 1);
    float a  = rb[(base     ) * 64 + o];
    float bb = rb[(base +  1) * 64 + o];
    float c  = rb[(base + 64) * 64 + o];
    float d  = rb[(base + 65) * 64 + o];
    float ll = 0.5f*(a+bb+c+d), lh = 0.5f*(a+bb-c-d);
    float hl = 0.5f*(a-bb+c-d), hh = 0.5f*(a-bb-c+d);
    float* outp = xd + (((b << 10) + (y << 5) + x) << 8) + o;
    outp[0]   = ll; outp[64]  = lh; outp[128] = hl; outp[192] = hh;
}

// ---------------- Haar IDWT ----------------
__global__ void idwt_kernel(const float* __restrict__ xd, float* __restrict__ xi)
{
    int t = blockIdx.x * 256 + threadIdx.x;
    int o = t & 63;
    int x = (t >> 6) & 31;
    int y = (t >> 11) & 31;
    int b = t >> 16;
    const float* p = xd + (((b << 10) + (y << 5) + x) << 8);
    float ll = p[o], lh = p[64+o], hl = p[128+o], hh = p[192+o];
    float y00 = 0.5f*(ll+lh+hl+hh);
    float y01 = 0.5f*(ll+lh-hl-hh);
    float y10 = 0.5f*(ll-lh+hl-hh);
    float y11 = 0.5f*(ll-lh-hl+hh);
    float* ob = xi + (b << 18);
    int base = ((y << 1) << 6) + (x << 1);
    ob[(base     ) * 64 + o] = y00;
    ob[(base +  1) * 64 + o] = y01;
    ob[(base + 64) * 64 + o] = y10;
    ob[(base + 65) * 64 + o] = y11;
}

// ---------------- LayerNorm over 256 ----------------
__launch_bounds__(256)
__global__ void ln_kernel(const float* __restrict__ X, const float* __restrict__ g,
                          const float* __restrict__ bta, float* __restrict__ Y)
{
    int row = blockIdx.x;
    int t = threadIdx.x;
    float x = X[row * 256 + t];
    __shared__ float red[4];
    int wv = t >> 6, ln = t & 63;
    float s = x;
    #pragma unroll
    for (int off = 32; off > 0; off >>= 1) s += __shfl_xor(s, off, 64);
    if (ln == 0) red[wv] = s;
    __syncthreads();
    float m = (red[0]+red[1]+red[2]+red[3]) * (1.f/256.f);
    float d = x - m;
    float s2 = d * d;
    #pragma unroll
    for (int off = 32; off > 0; off >>= 1) s2 += __shfl_xor(s2, off, 64);
    __syncthreads();
    if (ln == 0) red[wv] = s2;
    __syncthreads();
    float var = (red[0]+red[1]+red[2]+red[3]) * (1.f/256.f);
    float inv = 1.f / sqrtf(var + WEPS);
    Y[row * 256 + t] = d * inv * g[t] + bta[t];
}

// ---------------- MFMA flash attention ----------------
// qb: bf16 [B*4096][256]; kb: bf16 [16][1024][64]; vt: bf16 [16][64][1024]
// ow: f32 [B*4096][256]. Block = 4 waves, wave = 16 q rows. Grid (64, 16).
static __device__ inline bf16x8 lds_frag(const unsigned short* base, int row, int inner) {
    int byte = row * 128 + (inner ^ ((row & 7) << 4));
    return *(const bf16x8*)((const char*)base + byte);
}

__launch_bounds__(256)
__global__ void flash_mfma(const __hip_bfloat16* __restrict__ qb,
                           const __hip_bfloat16* __restrict__ kb,
                           const __hip_bfloat16* __restrict__ vt,
                           float* __restrict__ ow)
{
    __shared__ unsigned short Ks[4096];   // 64 keys x 64 d, XOR-swizzled rows
    __shared__ unsigned short Vs[4096];   // 64 d x 64 keys, XOR-swizzled rows
    const int tid = threadIdx.x;
    const int wv = tid >> 6;
    const int lane = tid & 63;
    const int g = lane >> 4, q16 = lane & 15;
    const int bh = blockIdx.y;
    const int b = bh >> 2, wh = bh & 3;
    const int qbase = (blockIdx.x << 6) + (wv << 4);

    // Q fragments (B-operand of swapped QK^T): lane holds Q[q16][dhalf*32 + g*8 + j]
    const __hip_bfloat16* qp = qb + ((size_t)((b << 12) + qbase + q16)) * 256 + wh * 64 + g * 8;
    bf16x8 qf0 = *(const bf16x8*)qp;
    bf16x8 qf1 = *(const bf16x8*)(qp + 32);

    const __hip_bfloat16* kbase = kb + ((size_t)bh << 16);
    const __hip_bfloat16* vbase = vt + ((size_t)bh << 16);

    f32x4 oacc[4];
    #pragma unroll
    for (int dc = 0; dc < 4; dc++)
        #pragma unroll
        for (int r = 0; r < 4; r++) oacc[dc][r] = 0.f;
    float m_old = -1e30f, lsum = 0.f;

    for (int t0 = 0; t0 < 1024; t0 += 64) {
        __syncthreads();
        // stage K tile (row-major [key][d]) and V tile (d-major [d][key]), swizzled
        #pragma unroll
        for (int it = 0; it < 2; it++) {
            int off = (tid << 4) + (it << 12);      // byte offset in 8KB tile
            int row = off >> 7;
            int inner = off & 127;
            int wb = row * 128 + (inner ^ ((row & 7) << 4));
            float4 kd = *(const float4*)(kbase + (t0 + row) * 64 + (inner >> 1));
            float4 vd = *(const float4*)(vbase + row * 1024 + t0 + (inner >> 1));
            *(float4*)((char*)Ks + wb) = kd;
            *(float4*)((char*)Vs + wb) = vd;
        }
        __syncthreads();

        // QK^T swapped: S^T[key, q] ; lane holds key = 16*sub + 4g + r, q = q16
        f32x4 st[4];
        #pragma unroll
        for (int sub = 0; sub < 4; sub++) {
            #pragma unroll
            for (int r = 0; r < 4; r++) st[sub][r] = 0.f;
            bf16x8 k0 = lds_frag(Ks, sub * 16 + q16, g * 16);
            bf16x8 k1 = lds_frag(Ks, sub * 16 + q16, 64 + g * 16);
            st[sub] = __builtin_amdgcn_mfma_f32_16x16x32_bf16(k0, qf0, st[sub], 0, 0, 0);
            st[sub] = __builtin_amdgcn_mfma_f32_16x16x32_bf16(k1, qf1, st[sub], 0, 0, 0);
        }

        // online softmax (per q = q16; 4 lanes share each q)
        float mx = -1e30f;
        float s[4][4];
        #pragma unroll
        for (int t = 0; t < 4; t++)
            #pragma unroll
            for (int r = 0; r < 4; r++) {
                float v = st[t][r] * WSCALE;
                s[t][r] = v;
                mx = fmaxf(mx, v);
            }
        mx = fmaxf(mx, __shfl_xor(mx, 16, 64));
        mx = fmaxf(mx, __shfl_xor(mx, 32, 64));
        float m_new = fmaxf(m_old, mx);
        float alpha = __expf(m_old - m_new);
        float psum = 0.f;
        unsigned pk[4][2];
        #pragma unroll
        for (int t = 0; t < 4; t++) {
            float p0 = __expf(s[t][0] - m_new), p1 = __expf(s[t][1] - m_new);
            float p2 = __expf(s[t][2] - m_new), p3 = __expf(s[t][3] - m_new);
            psum += (p0 + p1) + (p2 + p3);
            pk[t][0] = pack2bf(p0, p1);
            pk[t][1] = pack2bf(p2, p3);
        }
        psum += __shfl_xor(psum, 16, 64);
        psum += __shfl_xor(psum, 32, 64);
        lsum = lsum * alpha + psum;
        m_old = m_new;

        // rescale O (O rows are q = 4g + r)
        #pragma unroll
        for (int r = 0; r < 4; r++) {
            float sc = __shfl(alpha, (g << 2) + r, 64);
            #pragma unroll
            for (int dc = 0; dc < 4; dc++) oacc[dc][r] *= sc;
        }

        // redistribute P into PV A-fragments (static select avoids scratch)
        bool ghi = (g & 2) != 0;
        unsigned pkA0[2], pkA1[2];
        pkA0[0] = ghi ? pk[1][0] : pk[0][0];
        pkA0[1] = ghi ? pk[1][1] : pk[0][1];
        pkA1[0] = ghi ? pk[3][0] : pk[2][0];
        pkA1[1] = ghi ? pk[3][1] : pk[2][1];
        union { int u[4]; bf16x8 v; } A0, A1;
        #pragma unroll
        for (int c = 0; c < 4; c++) {
            int src = (((2 * g + (c >> 1)) & 3) << 4) | q16;
            A0.u[c] = __shfl((int)pkA0[c & 1], src, 64);
            A1.u[c] = __shfl((int)pkA1[c & 1], src, 64);
        }

        // PV: O[q, dc*16 + n] += P · V
        #pragma unroll
        for (int dc = 0; dc < 4; dc++) {
            bf16x8 v0 = lds_frag(Vs, dc * 16 + q16, g * 16);
            bf16x8 v1 = lds_frag(Vs, dc * 16 + q16, 64 + g * 16);
            oacc[dc] = __builtin_amdgcn_mfma_f32_16x16x32_bf16(A0.v, v0, oacc[dc], 0, 0, 0);
            oacc[dc] = __builtin_amdgcn_mfma_f32_16x16x32_bf16(A1.v, v1, oacc[dc], 0, 0, 0);
        }
    }

    // normalize + store: O row q = 4g + r, col d = dc*16 + q16
    #pragma unroll
    for (int r = 0; r < 4; r++) {
        float inv = 1.f / __shfl(lsum, (g << 2) + r, 64);
        int qrow = (b << 12) + qbase + (g << 2) + r;
        #pragma unroll
        for (int dc = 0; dc < 4; dc++)
            ow[(size_t)qrow * 256 + wh * 64 + dc * 16 + q16] = oacc[dc][r] * inv;
    }
}

extern "C" void kernel_launch(void* const* d_in, const int* in_sizes, int n_in,
                              void* d_out, int out_size, void* d_ws, size_t ws_size,
                              hipStream_t stream)
{
    const float* x        = (const float*)d_in[0];
    const float* wq_w     = (const float*)d_in[1];
    const float* kv_ln_g  = (const float*)d_in[2];
    const float* kv_ln_b  = (const float*)d_in[3];
    const float* wkv_w    = (const float*)d_in[4];
    const float* wkv_b    = (const float*)d_in[5];
    const float* wproj_w  = (const float*)d_in[6];
    const float* wproj_b  = (const float*)d_in[7];
    const float* reduce_w = (const float*)d_in[8];
    const float* reduce_b = (const float*)d_in[9];
    const float* rbn_g    = (const float*)d_in[10];
    const float* rbn_b    = (const float*)d_in[11];
    const float* filter_w = (const float*)d_in[12];
    const float* filter_b = (const float*)d_in[13];
    const float* fbn_g    = (const float*)d_in[14];
    const float* fbn_b    = (const float*)d_in[15];
    const float* sqkv_w   = (const float*)d_in[16];
    const float* sproj_w  = (const float*)d_in[17];
    const float* sproj_b  = (const float*)d_in[18];
    float* out = (float*)d_out;
    float* ws  = (float*)d_ws;

    // workspace layout (float units)
    float* qkv   = ws;                       // 12,582,912
    float* ow    = ws;                       // reuse (qkv dead after win_attn)
    float* sa_o  = ws + 12582912;            // 4,194,304
    float* wt    = ws + 12582912;            // reuse (sa_o dead after sproj)
    float* rbuf  = ws + 16777216;            // 1,048,576
    float* xd1   = ws + 17825792;            // 1,048,576
    float* xd2   = ws + 18874368;            // 1,048,576
    float* kvin  = ws + 19922944;            // 1,048,576
    float* xidwt = ws + 20971520;            // 1,048,576
    __hip_bfloat16* qbw = (__hip_bfloat16*)(ws + 22020096);  // 4,194,304 bf16
    __hip_bfloat16* kbb = (__hip_bfloat16*)(ws + 24117248);  // 1,048,576 bf16
    __hip_bfloat16* vtb = (__hip_bfloat16*)(ws + 24641536);  // 1,048,576 bf16

    dim3 blk(256);

    // 1. qkv = x @ sqkv_w            (M=16384, N=768, K=512)
    gemm_f32<EPI_NONE,0><<<dim3(6,128), blk, 0, stream>>>(x, 512, sqkv_w, 768, qkv, 768,
                                                          768, 512, nullptr, nullptr, nullptr);
    // 2. window attention
    win_attn<<<dim3(4096), blk, 0, stream>>>(qkv, sa_o);
    // 3. sa_out -> out cols [0,256)
    gemm_f32<EPI_BIAS,0><<<dim3(2,128), blk, 0, stream>>>(sa_o, 256, sproj_w, 256, out, 512,
                                                          256, 256, sproj_b, nullptr, nullptr);
    // 4. qw (bf16) = x @ wq_w
    gemm_f32<EPI_NONE,1><<<dim3(2,128), blk, 0, stream>>>(x, 512, wq_w, 256, qbw, 256,
                                                          256, 512, nullptr, nullptr, nullptr);
    // 5. r = relu(bn(x @ reduce_w + b))
    gemm_f32<EPI_BN_RELU,0><<<dim3(1,128), blk, 0, stream>>>(x, 512, reduce_w, 64, rbuf, 64,
                                                             64, 512, reduce_b, rbn_g, rbn_b);
    // 6. conv weight transpose
    wt_kernel<<<dim3(2304), blk, 0, stream>>>(filter_w, wt);
    // 7. DWT
    dwt_kernel<<<dim3(1024), blk, 0, stream>>>(rbuf, xd1);
    // 8. 3x3 conv + BN + ReLU
    conv3_gemm<<<dim3(2,32), blk, 0, stream>>>(xd1, wt, xd2, filter_b, fbn_g, fbn_b);
    // 9. layernorm
    ln_kernel<<<dim3(4096), blk, 0, stream>>>(xd2, kv_ln_g, kv_ln_b, kvin);
    // 10. kv GEMM -> bf16 K + transposed V
    gemm_kv<<<dim3(4,32), blk, 0, stream>>>(kvin, wkv_w, kbb, vtb, wkv_b);
    // 11. IDWT
    idwt_kernel<<<dim3(1024), blk, 0, stream>>>(xd2, xidwt);
    // 12. MFMA flash attention
    flash_mfma<<<dim3(64,16), blk, 0, stream>>>(qbw, kbb, vtb, ow);
    // 13. wa = ow @ wproj_w[0:256] + b -> out cols [256,512)
    gemm_f32<EPI_BIAS,0><<<dim3(2,128), blk, 0, stream>>>(ow, 256, wproj_w, 256, out + 256, 512,
                                                          256, 256, wproj_b, nullptr, nullptr);
    // 14. wa += x_idwt @ wproj_w[256:320]
    gemm_f32<EPI_ACC,0><<<dim3(2,128), blk, 0, stream>>>(xidwt, 64, wproj_w + 256*256, 256,
                                                         out + 256, 512, 256, 64,
                                                         nullptr, nullptr, nullptr);
}

// Round 3
// 605.497 us; speedup vs baseline: 2.6959x; 1.4404x over previous
//
#include <hip/hip_runtime.h>
#include <hip/hip_bf16.h>
#include <math.h>

#define WEPS 1e-5f
#define WSCALE 0.125f

enum { EPI_NONE=0, EPI_BIAS=1, EPI_BN_RELU=2, EPI_ACC=3 };

typedef __attribute__((ext_vector_type(8))) short bf16x8;
typedef __attribute__((ext_vector_type(4))) float f32x4;
typedef __attribute__((ext_vector_type(8))) unsigned short ushort8;

static __device__ inline unsigned short f2bf(float f) {
    __hip_bfloat16 h = __float2bfloat16(f);
    return *(unsigned short*)&h;
}
static __device__ inline unsigned pack2bf(float a, float b) {
    return (unsigned)f2bf(a) | ((unsigned)f2bf(b) << 16);
}

// swizzled LDS 16B fragment read: rows are 128B, byte ^= (row&7)<<4
static __device__ inline bf16x8 lds_frag(const unsigned short* base, int row, int inner) {
    int byte = row * 128 + (inner ^ ((row & 7) << 4));
    return *(const bf16x8*)((const char*)base + byte);
}

// ---------------- generic fp32 GEMM ----------------
template<int EPI, int OBF16>
__launch_bounds__(256)
__global__ void gemm_f32(const float* __restrict__ A, int lda,
                         const float* __restrict__ B, int ldb,
                         void* __restrict__ Cv, int ldc,
                         int N, int K,
                         const float* __restrict__ bias,
                         const float* __restrict__ bn_g,
                         const float* __restrict__ bn_b)
{
    __shared__ float As[16][132];
    __shared__ float Bs[16][132];
    const int bm = blockIdx.y << 7;
    const int bn = blockIdx.x << 7;
    const int tid = threadIdx.x;
    const int tx = tid & 15, ty = tid >> 4;
    float acc[8][8] = {};
    for (int k0 = 0; k0 < K; k0 += 16) {
        #pragma unroll
        for (int i = 0; i < 2; i++) {
            int idx = tid + (i << 8);
            int m  = idx >> 2;
            int c4 = (idx & 3) << 2;
            float4 v = *(const float4*)(A + (bm + m) * lda + k0 + c4);
            As[c4+0][m] = v.x; As[c4+1][m] = v.y; As[c4+2][m] = v.z; As[c4+3][m] = v.w;
        }
        #pragma unroll
        for (int i = 0; i < 2; i++) {
            int idx = tid + (i << 8);
            int kk = idx >> 5;
            int n4 = (idx & 31) << 2;
            int col = bn + n4;
            float4 v = make_float4(0.f,0.f,0.f,0.f);
            if (col < N) v = *(const float4*)(B + (k0 + kk) * ldb + col);
            *(float4*)&Bs[kk][n4] = v;
        }
        __syncthreads();
        #pragma unroll
        for (int kk = 0; kk < 16; kk++) {
            float a0[8], b0[8];
            #pragma unroll
            for (int i = 0; i < 8; i++) a0[i] = As[kk][(ty<<3)+i];
            #pragma unroll
            for (int j = 0; j < 8; j++) b0[j] = Bs[kk][(tx<<3)+j];
            #pragma unroll
            for (int i = 0; i < 8; i++)
                #pragma unroll
                for (int j = 0; j < 8; j++)
                    acc[i][j] = fmaf(a0[i], b0[j], acc[i][j]);
        }
        __syncthreads();
    }
    const float bn_s = 0.99999500003749968f;
    if (OBF16) {
        __hip_bfloat16* C = (__hip_bfloat16*)Cv;
        #pragma unroll
        for (int i = 0; i < 8; i++) {
            int row = bm + (ty<<3) + i;
            int col0 = bn + (tx<<3);
            ushort8 h;
            #pragma unroll
            for (int j = 0; j < 8; j++) {
                float t = acc[i][j];
                if (EPI == EPI_BIAS) t += bias[col0 + j];
                h[j] = f2bf(t);
            }
            *(ushort8*)(C + (size_t)row * ldc + col0) = h;
        }
        return;
    }
    float* C = (float*)Cv;
    #pragma unroll
    for (int i = 0; i < 8; i++) {
        int row = bm + (ty<<3) + i;
        #pragma unroll
        for (int j4 = 0; j4 < 2; j4++) {
            int col = bn + (tx<<3) + (j4<<2);
            if (col >= N) continue;
            float v[4];
            #pragma unroll
            for (int j = 0; j < 4; j++) {
                float t = acc[i][(j4<<2)+j];
                int c = col + j;
                if (EPI == EPI_BIAS) t += bias[c];
                if (EPI == EPI_BN_RELU) {
                    float s = bn_g[c] * bn_s;
                    t = fmaxf((t + bias[c]) * s + bn_b[c], 0.f);
                }
                v[j] = t;
            }
            float* cp = C + row * ldc + col;
            if (EPI == EPI_ACC) {
                float4 old = *(const float4*)cp;
                v[0]+=old.x; v[1]+=old.y; v[2]+=old.z; v[3]+=old.w;
            }
            *(float4*)cp = make_float4(v[0],v[1],v[2],v[3]);
        }
    }
}

// ---------------- kv GEMM: fp32 compute, bf16 K (row-major) + V (transposed) out ----------
__launch_bounds__(256)
__global__ void gemm_kv(const float* __restrict__ A,
                        const float* __restrict__ B,
                        __hip_bfloat16* __restrict__ kbo,   // [16][1024][64]
                        __hip_bfloat16* __restrict__ vto,   // [16][64][1024]
                        const float* __restrict__ bias)
{
    __shared__ float As[16][132];
    __shared__ float Bs[16][132];
    const int bm = blockIdx.y << 7;
    const int bn = blockIdx.x << 7;
    const int tid = threadIdx.x;
    const int tx = tid & 15, ty = tid >> 4;
    float acc[8][8] = {};
    for (int k0 = 0; k0 < 256; k0 += 16) {
        #pragma unroll
        for (int i = 0; i < 2; i++) {
            int idx = tid + (i << 8);
            int m  = idx >> 2;
            int c4 = (idx & 3) << 2;
            float4 v = *(const float4*)(A + (bm + m) * 256 + k0 + c4);
            As[c4+0][m] = v.x; As[c4+1][m] = v.y; As[c4+2][m] = v.z; As[c4+3][m] = v.w;
        }
        #pragma unroll
        for (int i = 0; i < 2; i++) {
            int idx = tid + (i << 8);
            int kk = idx >> 5;
            int n4 = (idx & 31) << 2;
            float4 v = *(const float4*)(B + (k0 + kk) * 512 + bn + n4);
            *(float4*)&Bs[kk][n4] = v;
        }
        __syncthreads();
        #pragma unroll
        for (int kk = 0; kk < 16; kk++) {
            float a0[8], b0[8];
            #pragma unroll
            for (int i = 0; i < 8; i++) a0[i] = As[kk][(ty<<3)+i];
            #pragma unroll
            for (int j = 0; j < 8; j++) b0[j] = Bs[kk][(tx<<3)+j];
            #pragma unroll
            for (int i = 0; i < 8; i++)
                #pragma unroll
                for (int j = 0; j < 8; j++)
                    acc[i][j] = fmaf(a0[i], b0[j], acc[i][j]);
        }
        __syncthreads();
    }
    if (bn < 256) {                 // K part: row-major [bh][token][d]
        #pragma unroll
        for (int i = 0; i < 8; i++) {
            int row = bm + (ty<<3) + i;
            int b = row >> 10, tkn = row & 1023;
            int col0 = bn + (tx<<3);
            int wh = col0 >> 6, d0 = col0 & 63;
            ushort8 h;
            #pragma unroll
            for (int j = 0; j < 8; j++) h[j] = f2bf(acc[i][j] + bias[col0 + j]);
            *(ushort8*)(kbo + (((size_t)((b<<2)+wh)) << 16) + tkn*64 + d0) = h;
        }
    } else {                        // V part: transposed [bh][d][token]
        int row0 = bm + (ty<<3);
        int b = row0 >> 10, tkn0 = row0 & 1023;
        #pragma unroll
        for (int j = 0; j < 8; j++) {
            int c = bn - 256 + (tx<<3) + j;
            int wh = c >> 6, d = c & 63;
            ushort8 h;
            #pragma unroll
            for (int i = 0; i < 8; i++) h[i] = f2bf(acc[i][j] + bias[256 + c]);
            *(ushort8*)(vto + (((size_t)((b<<2)+wh)) << 16) + d*1024 + tkn0) = h;
        }
    }
}

// ---------------- 3x3 conv: bf16 MFMA implicit-im2col GEMM ----------------
// Xd: bf16 [B*1024][256] channel-last (32x32 spatial). Wt: bf16 [256 out][2304 k],
// k = tap*256 + ci. Out xd2 fp32 [B*1024][256] with BN+ReLU.
// 128x128 tile, BK=64, 4 waves x (64x64). Grid (2, 32).
__launch_bounds__(256)
__global__ void conv3_mfma(const __hip_bfloat16* __restrict__ Xd,
                           const __hip_bfloat16* __restrict__ Wt,
                           float* __restrict__ C,
                           const float* __restrict__ bias,
                           const float* __restrict__ bn_g,
                           const float* __restrict__ bn_b)
{
    __shared__ unsigned short As[8192];   // 128 rows x 64 k (swizzled 128B rows)
    __shared__ unsigned short Bs[8192];   // 128 cols x 64 k
    const int tid = threadIdx.x;
    const int lane = tid & 63, wv = tid >> 6;
    const int g = lane >> 4, l16 = lane & 15;
    const int wr = wv >> 1, wc = wv & 1;
    const int bm = blockIdx.y << 7;
    const int bn = blockIdx.x << 7;
    f32x4 acc[4][4];
    #pragma unroll
    for (int i = 0; i < 4; i++)
        #pragma unroll
        for (int j = 0; j < 4; j++)
            #pragma unroll
            for (int r = 0; r < 4; r++) acc[i][j][r] = 0.f;

    for (int k0 = 0; k0 < 2304; k0 += 64) {
        int tap = k0 >> 8;
        int dy = tap / 3 - 1;
        int dx = tap - (tap / 3) * 3 - 1;
        int i0 = k0 & 255;
        __syncthreads();
        #pragma unroll
        for (int it = 0; it < 4; it++) {
            int idx = tid + (it << 8);          // 0..1023 = 128 rows x 8 segs
            int row = idx >> 3, seg = idx & 7;
            int wb = row * 128 + ((seg << 4) ^ ((row & 7) << 4));
            // A: shifted xd row (SAME padding -> zero)
            int m = bm + row;
            int bimg = m >> 10, s = m & 1023;
            int y = (s >> 5) + dy, xx = (s & 31) + dx;
            float4 av = make_float4(0.f,0.f,0.f,0.f);
            if ((unsigned)y < 32u && (unsigned)xx < 32u)
                av = *(const float4*)(Xd + ((((bimg<<10) + (y<<5) + xx)) << 8) + i0 + (seg<<3));
            *(float4*)((char*)As + wb) = av;
            // B: weight row (col-major operand: contiguous k per out-channel)
            float4 bv = *(const float4*)(Wt + (size_t)(bn + row) * 2304 + k0 + (seg<<3));
            *(float4*)((char*)Bs + wb) = bv;
        }
        __syncthreads();
        #pragma unroll
        for (int ks = 0; ks < 2; ks++) {
            bf16x8 af[4], bfr[4];
            #pragma unroll
            for (int i = 0; i < 4; i++)
                af[i] = lds_frag(As, (wr<<6) + (i<<4) + l16, (ks<<6) + (g<<4));
            #pragma unroll
            for (int j = 0; j < 4; j++)
                bfr[j] = lds_frag(Bs, (wc<<6) + (j<<4) + l16, (ks<<6) + (g<<4));
            #pragma unroll
            for (int i = 0; i < 4; i++)
                #pragma unroll
                for (int j = 0; j < 4; j++)
                    acc[i][j] = __builtin_amdgcn_mfma_f32_16x16x32_bf16(af[i], bfr[j], acc[i][j], 0, 0, 0);
        }
    }
    const float bn_s = 0.99999500003749968f;
    #pragma unroll
    for (int i = 0; i < 4; i++) {
        int m = bm + (wr<<6) + (i<<4) + (g<<2);
        #pragma unroll
        for (int j = 0; j < 4; j++) {
            int c = bn + (wc<<6) + (j<<4) + l16;
            float sc = bn_g[c] * bn_s, bb = bn_b[c], bi = bias[c];
            #pragma unroll
            for (int r = 0; r < 4; r++)
                C[(size_t)(m + r) * 256 + c] = fmaxf((acc[i][j][r] + bi) * sc + bb, 0.f);
        }
    }
}

// ---------------- filter weight transpose -> bf16 [o][tap*256+i] ----------------
__global__ void wt_kernel(const float* __restrict__ Wf, __hip_bfloat16* __restrict__ Wt)
{
    int o = blockIdx.x;      // 0..255
    int i = threadIdx.x;     // 0..255
    const float* src = Wf + (size_t)(o * 256 + i) * 9;
    __hip_bfloat16* dst = Wt + (size_t)o * 2304 + i;
    #pragma unroll
    for (int tap = 0; tap < 9; tap++)
        dst[tap * 256] = __float2bfloat16(src[tap]);
}

// ---------------- window attention ----------------
__launch_bounds__(256)
__global__ void win_attn(const float* __restrict__ qkv, float* __restrict__ sa_o)
{
    int gw = blockIdx.x * 4 + (threadIdx.x >> 6);
    int lane = threadIdx.x & 63;
    int b  = gw >> 12;
    int g  = (gw >> 2) & 1023;
    int sh = gw & 3;
    int hg = g >> 5, wg = g & 31;
    float q[4], k[4], v[4];
    int rows[4];
    #pragma unroll
    for (int l = 0; l < 4; l++) {
        int h = (hg << 1) + (l >> 1), w = (wg << 1) + (l & 1);
        int row = (b << 12) + (h << 6) + w;
        rows[l] = row;
        const float* p = qkv + row * 768 + sh * 64 + lane;
        q[l] = p[0]; k[l] = p[256]; v[l] = p[512];
    }
    float s[4][4];
    #pragma unroll
    for (int l = 0; l < 4; l++)
        #pragma unroll
        for (int m = 0; m < 4; m++) s[l][m] = q[l] * k[m];
    #pragma unroll
    for (int off = 32; off > 0; off >>= 1)
        #pragma unroll
        for (int l = 0; l < 4; l++)
            #pragma unroll
            for (int m = 0; m < 4; m++)
                s[l][m] += __shfl_xor(s[l][m], off, 64);
    #pragma unroll
    for (int l = 0; l < 4; l++) {
        float s0 = s[l][0]*WSCALE, s1 = s[l][1]*WSCALE, s2 = s[l][2]*WSCALE, s3 = s[l][3]*WSCALE;
        float mx = fmaxf(fmaxf(s0,s1), fmaxf(s2,s3));
        float p0 = __expf(s0-mx), p1 = __expf(s1-mx), p2 = __expf(s2-mx), p3 = __expf(s3-mx);
        float inv = 1.f / (p0+p1+p2+p3);
        float o = (p0*v[0] + p1*v[1] + p2*v[2] + p3*v[3]) * inv;
        sa_o[rows[l] * 256 + sh * 64 + lane] = o;
    }
}

// ---------------- Haar DWT -> bf16 channel-last ----------------
__global__ void dwt_kernel(const float* __restrict__ r, __hip_bfloat16* __restrict__ xd)
{
    int t = blockIdx.x * 256 + threadIdx.x;
    int o = t & 63;
    int x = (t >> 6) & 31;
    int y = (t >> 11) & 31;
    int b = t >> 16;
    const float* rb = r + (b << 18);
    int base = ((y << 1) << 6) + (x << 1);
    float a  = rb[(base     ) * 64 + o];
    float bb = rb[(base +  1) * 64 + o];
    float c  = rb[(base + 64) * 64 + o];
    float d  = rb[(base + 65) * 64 + o];
    float ll = 0.5f*(a+bb+c+d), lh = 0.5f*(a+bb-c-d);
    float hl = 0.5f*(a-bb+c-d), hh = 0.5f*(a-bb-c+d);
    __hip_bfloat16* outp = xd + (((b << 10) + (y << 5) + x) << 8) + o;
    outp[0]   = __float2bfloat16(ll);
    outp[64]  = __float2bfloat16(lh);
    outp[128] = __float2bfloat16(hl);
    outp[192] = __float2bfloat16(hh);
}

// ---------------- Haar IDWT (fp32 xd2 in) ----------------
__global__ void idwt_kernel(const float* __restrict__ xd, float* __restrict__ xi)
{
    int t = blockIdx.x * 256 + threadIdx.x;
    int o = t & 63;
    int x = (t >> 6) & 31;
    int y = (t >> 11) & 31;
    int b = t >> 16;
    const float* p = xd + (((b << 10) + (y << 5) + x) << 8);
    float ll = p[o], lh = p[64+o], hl = p[128+o], hh = p[192+o];
    float y00 = 0.5f*(ll+lh+hl+hh);
    float y01 = 0.5f*(ll+lh-hl-hh);
    float y10 = 0.5f*(ll-lh+hl-hh);
    float y11 = 0.5f*(ll-lh-hl+hh);
    float* ob = xi + (b << 18);
    int base = ((y << 1) << 6) + (x << 1);
    ob[(base     ) * 64 + o] = y00;
    ob[(base +  1) * 64 + o] = y01;
    ob[(base + 64) * 64 + o] = y10;
    ob[(base + 65) * 64 + o] = y11;
}

// ---------------- LayerNorm over 256 ----------------
__launch_bounds__(256)
__global__ void ln_kernel(const float* __restrict__ X, const float* __restrict__ g,
                          const float* __restrict__ bta, float* __restrict__ Y)
{
    int row = blockIdx.x;
    int t = threadIdx.x;
    float x = X[row * 256 + t];
    __shared__ float red[4];
    int wv = t >> 6, ln = t & 63;
    float s = x;
    #pragma unroll
    for (int off = 32; off > 0; off >>= 1) s += __shfl_xor(s, off, 64);
    if (ln == 0) red[wv] = s;
    __syncthreads();
    float m = (red[0]+red[1]+red[2]+red[3]) * (1.f/256.f);
    float d = x - m;
    float s2 = d * d;
    #pragma unroll
    for (int off = 32; off > 0; off >>= 1) s2 += __shfl_xor(s2, off, 64);
    __syncthreads();
    if (ln == 0) red[wv] = s2;
    __syncthreads();
    float var = (red[0]+red[1]+red[2]+red[3]) * (1.f/256.f);
    float inv = 1.f / sqrtf(var + WEPS);
    Y[row * 256 + t] = d * inv * g[t] + bta[t];
}

// ---------------- MFMA flash attention ----------------
__launch_bounds__(256)
__global__ void flash_mfma(const __hip_bfloat16* __restrict__ qb,
                           const __hip_bfloat16* __restrict__ kb,
                           const __hip_bfloat16* __restrict__ vt,
                           float* __restrict__ ow)
{
    __shared__ unsigned short Ks[4096];
    __shared__ unsigned short Vs[4096];
    const int tid = threadIdx.x;
    const int wv = tid >> 6;
    const int lane = tid & 63;
    const int g = lane >> 4, q16 = lane & 15;
    const int bh = blockIdx.y;
    const int b = bh >> 2, wh = bh & 3;
    const int qbase = (blockIdx.x << 6) + (wv << 4);

    const __hip_bfloat16* qp = qb + ((size_t)((b << 12) + qbase + q16)) * 256 + wh * 64 + g * 8;
    bf16x8 qf0 = *(const bf16x8*)qp;
    bf16x8 qf1 = *(const bf16x8*)(qp + 32);

    const __hip_bfloat16* kbase = kb + ((size_t)bh << 16);
    const __hip_bfloat16* vbase = vt + ((size_t)bh << 16);

    f32x4 oacc[4];
    #pragma unroll
    for (int dc = 0; dc < 4; dc++)
        #pragma unroll
        for (int r = 0; r < 4; r++) oacc[dc][r] = 0.f;
    float m_old = -1e30f, lsum = 0.f;

    for (int t0 = 0; t0 < 1024; t0 += 64) {
        __syncthreads();
        #pragma unroll
        for (int it = 0; it < 2; it++) {
            int off = (tid << 4) + (it << 12);
            int row = off >> 7;
            int inner = off & 127;
            int wb = row * 128 + (inner ^ ((row & 7) << 4));
            float4 kd = *(const float4*)(kbase + (t0 + row) * 64 + (inner >> 1));
            float4 vd = *(const float4*)(vbase + row * 1024 + t0 + (inner >> 1));
            *(float4*)((char*)Ks + wb) = kd;
            *(float4*)((char*)Vs + wb) = vd;
        }
        __syncthreads();

        f32x4 st[4];
        #pragma unroll
        for (int sub = 0; sub < 4; sub++) {
            #pragma unroll
            for (int r = 0; r < 4; r++) st[sub][r] = 0.f;
            bf16x8 k0 = lds_frag(Ks, sub * 16 + q16, g * 16);
            bf16x8 k1 = lds_frag(Ks, sub * 16 + q16, 64 + g * 16);
            st[sub] = __builtin_amdgcn_mfma_f32_16x16x32_bf16(k0, qf0, st[sub], 0, 0, 0);
            st[sub] = __builtin_amdgcn_mfma_f32_16x16x32_bf16(k1, qf1, st[sub], 0, 0, 0);
        }

        float mx = -1e30f;
        float s[4][4];
        #pragma unroll
        for (int t = 0; t < 4; t++)
            #pragma unroll
            for (int r = 0; r < 4; r++) {
                float v = st[t][r] * WSCALE;
                s[t][r] = v;
                mx = fmaxf(mx, v);
            }
        mx = fmaxf(mx, __shfl_xor(mx, 16, 64));
        mx = fmaxf(mx, __shfl_xor(mx, 32, 64));
        float m_new = fmaxf(m_old, mx);
        float alpha = __expf(m_old - m_new);
        float psum = 0.f;
        unsigned pk[4][2];
        #pragma unroll
        for (int t = 0; t < 4; t++) {
            float p0 = __expf(s[t][0] - m_new), p1 = __expf(s[t][1] - m_new);
            float p2 = __expf(s[t][2] - m_new), p3 = __expf(s[t][3] - m_new);
            psum += (p0 + p1) + (p2 + p3);
            pk[t][0] = pack2bf(p0, p1);
            pk[t][1] = pack2bf(p2, p3);
        }
        psum += __shfl_xor(psum, 16, 64);
        psum += __shfl_xor(psum, 32, 64);
        lsum = lsum * alpha + psum;
        m_old = m_new;

        #pragma unroll
        for (int r = 0; r < 4; r++) {
            float sc = __shfl(alpha, (g << 2) + r, 64);
            #pragma unroll
            for (int dc = 0; dc < 4; dc++) oacc[dc][r] *= sc;
        }

        bool ghi = (g & 2) != 0;
        unsigned pkA0[2], pkA1[2];
        pkA0[0] = ghi ? pk[1][0] : pk[0][0];
        pkA0[1] = ghi ? pk[1][1] : pk[0][1];
        pkA1[0] = ghi ? pk[3][0] : pk[2][0];
        pkA1[1] = ghi ? pk[3][1] : pk[2][1];
        union { int u[4]; bf16x8 v; } A0, A1;
        #pragma unroll
        for (int c = 0; c < 4; c++) {
            int src = (((2 * g + (c >> 1)) & 3) << 4) | q16;
            A0.u[c] = __shfl((int)pkA0[c & 1], src, 64);
            A1.u[c] = __shfl((int)pkA1[c & 1], src, 64);
        }

        #pragma unroll
        for (int dc = 0; dc < 4; dc++) {
            bf16x8 v0 = lds_frag(Vs, dc * 16 + q16, g * 16);
            bf16x8 v1 = lds_frag(Vs, dc * 16 + q16, 64 + g * 16);
            oacc[dc] = __builtin_amdgcn_mfma_f32_16x16x32_bf16(A0.v, v0, oacc[dc], 0, 0, 0);
            oacc[dc] = __builtin_amdgcn_mfma_f32_16x16x32_bf16(A1.v, v1, oacc[dc], 0, 0, 0);
        }
    }

    #pragma unroll
    for (int r = 0; r < 4; r++) {
        float inv = 1.f / __shfl(lsum, (g << 2) + r, 64);
        int qrow = (b << 12) + qbase + (g << 2) + r;
        #pragma unroll
        for (int dc = 0; dc < 4; dc++)
            ow[(size_t)qrow * 256 + wh * 64 + dc * 16 + q16] = oacc[dc][r] * inv;
    }
}

extern "C" void kernel_launch(void* const* d_in, const int* in_sizes, int n_in,
                              void* d_out, int out_size, void* d_ws, size_t ws_size,
                              hipStream_t stream)
{
    const float* x        = (const float*)d_in[0];
    const float* wq_w     = (const float*)d_in[1];
    const float* kv_ln_g  = (const float*)d_in[2];
    const float* kv_ln_b  = (const float*)d_in[3];
    const float* wkv_w    = (const float*)d_in[4];
    const float* wkv_b    = (const float*)d_in[5];
    const float* wproj_w  = (const float*)d_in[6];
    const float* wproj_b  = (const float*)d_in[7];
    const float* reduce_w = (const float*)d_in[8];
    const float* reduce_b = (const float*)d_in[9];
    const float* rbn_g    = (const float*)d_in[10];
    const float* rbn_b    = (const float*)d_in[11];
    const float* filter_w = (const float*)d_in[12];
    const float* filter_b = (const float*)d_in[13];
    const float* fbn_g    = (const float*)d_in[14];
    const float* fbn_b    = (const float*)d_in[15];
    const float* sqkv_w   = (const float*)d_in[16];
    const float* sproj_w  = (const float*)d_in[17];
    const float* sproj_b  = (const float*)d_in[18];
    float* out = (float*)d_out;
    float* ws  = (float*)d_ws;

    // workspace layout (float units)
    float* qkv   = ws;                       // 12,582,912
    float* ow    = ws;                       // reuse (qkv dead after win_attn)
    float* sa_o  = ws + 12582912;            // 4,194,304
    __hip_bfloat16* wt2b = (__hip_bfloat16*)(ws + 12582912);  // reuse (sa_o dead after sproj); 589,824 bf16
    float* rbuf  = ws + 16777216;            // 1,048,576
    __hip_bfloat16* xd1b = (__hip_bfloat16*)(ws + 17825792); // 1,048,576 bf16
    float* xd2   = ws + 18874368;            // 1,048,576
    float* kvin  = ws + 19922944;            // 1,048,576
    float* xidwt = ws + 20971520;            // 1,048,576
    __hip_bfloat16* qbw = (__hip_bfloat16*)(ws + 22020096);  // 4,194,304 bf16
    __hip_bfloat16* kbb = (__hip_bfloat16*)(ws + 24117248);  // 1,048,576 bf16
    __hip_bfloat16* vtb = (__hip_bfloat16*)(ws + 24641536);  // 1,048,576 bf16

    dim3 blk(256);

    // 1. qkv = x @ sqkv_w            (M=16384, N=768, K=512)
    gemm_f32<EPI_NONE,0><<<dim3(6,128), blk, 0, stream>>>(x, 512, sqkv_w, 768, qkv, 768,
                                                          768, 512, nullptr, nullptr, nullptr);
    // 2. window attention
    win_attn<<<dim3(4096), blk, 0, stream>>>(qkv, sa_o);
    // 3. sa_out -> out cols [0,256)
    gemm_f32<EPI_BIAS,0><<<dim3(2,128), blk, 0, stream>>>(sa_o, 256, sproj_w, 256, out, 512,
                                                          256, 256, sproj_b, nullptr, nullptr);
    // 4. qw (bf16) = x @ wq_w
    gemm_f32<EPI_NONE,1><<<dim3(2,128), blk, 0, stream>>>(x, 512, wq_w, 256, qbw, 256,
                                                          256, 512, nullptr, nullptr, nullptr);
    // 5. r = relu(bn(x @ reduce_w + b))
    gemm_f32<EPI_BN_RELU,0><<<dim3(1,128), blk, 0, stream>>>(x, 512, reduce_w, 64, rbuf, 64,
                                                             64, 512, reduce_b, rbn_g, rbn_b);
    // 6. conv weight transpose -> bf16 [o][k]
    wt_kernel<<<dim3(256), blk, 0, stream>>>(filter_w, wt2b);
    // 7. DWT -> bf16
    dwt_kernel<<<dim3(1024), blk, 0, stream>>>(rbuf, xd1b);
    // 8. 3x3 conv MFMA + BN + ReLU
    conv3_mfma<<<dim3(2,32), blk, 0, stream>>>(xd1b, wt2b, xd2, filter_b, fbn_g, fbn_b);
    // 9. layernorm
    ln_kernel<<<dim3(4096), blk, 0, stream>>>(xd2, kv_ln_g, kv_ln_b, kvin);
    // 10. kv GEMM -> bf16 K + transposed V
    gemm_kv<<<dim3(4,32), blk, 0, stream>>>(kvin, wkv_w, kbb, vtb, wkv_b);
    // 11. IDWT
    idwt_kernel<<<dim3(1024), blk, 0, stream>>>(xd2, xidwt);
    // 12. MFMA flash attention
    flash_mfma<<<dim3(64,16), blk, 0, stream>>>(qbw, kbb, vtb, ow);
    // 13. wa = ow @ wproj_w[0:256] + b -> out cols [256,512)
    gemm_f32<EPI_BIAS,0><<<dim3(2,128), blk, 0, stream>>>(ow, 256, wproj_w, 256, out + 256, 512,
                                                          256, 256, wproj_b, nullptr, nullptr);
    // 14. wa += x_idwt @ wproj_w[256:320]
    gemm_f32<EPI_ACC,0><<<dim3(2,128), blk, 0, stream>>>(xidwt, 64, wproj_w + 256*256, 256,
                                                         out + 256, 512, 256, 64,
                                                         nullptr, nullptr, nullptr);
}

// Round 4
// 264.401 us; speedup vs baseline: 6.1738x; 2.2901x over previous
//
#include <hip/hip_runtime.h>
#include <hip/hip_bf16.h>
#include <math.h>

#define WEPS 1e-5f
#define WSCALE 0.125f

enum { EPI_NONE=0, EPI_BIAS=1, EPI_BN_RELU=2 };

typedef __attribute__((ext_vector_type(8))) short bf16x8;
typedef __attribute__((ext_vector_type(4))) float f32x4;

static __device__ inline unsigned short f2bf(float f) {
    __hip_bfloat16 h = __float2bfloat16(f);
    return *(unsigned short*)&h;
}
static __device__ inline unsigned pack2bf(float a, float b) {
    return (unsigned)f2bf(a) | ((unsigned)f2bf(b) << 16);
}

// swizzled LDS 16B fragment read: rows are 128B, byte ^= (row&7)<<4
static __device__ inline bf16x8 lds_frag(const unsigned short* base, int row, int inner) {
    int byte = row * 128 + (inner ^ ((row & 7) << 4));
    return *(const bf16x8*)((const char*)base + byte);
}

// ================= bf16 MFMA GEMM template =================
// C[M,N] = A[M,K](bf16,row-major) @ Bt[N,K](bf16)^T. 128x128 tile, BK=64,
// 4 waves x 64x64. M mult 128, K mult 64; N col-guarded.
template<int EPI, int OBF16>
__launch_bounds__(256)
__global__ void gemm_bf16(const __hip_bfloat16* __restrict__ A, int lda,
                          const __hip_bfloat16* __restrict__ Bt, int K,
                          void* __restrict__ Cv, int ldc, int N,
                          const float* __restrict__ bias,
                          const float* __restrict__ bn_g,
                          const float* __restrict__ bn_b)
{
    __shared__ unsigned short As[8192];
    __shared__ unsigned short Bs[8192];
    const int tid = threadIdx.x;
    const int lane = tid & 63, wv = tid >> 6;
    const int g = lane >> 4, l16 = lane & 15;
    const int wr = wv >> 1, wc = wv & 1;
    const int bm = blockIdx.y << 7;
    const int bn = blockIdx.x << 7;
    f32x4 acc[4][4];
    #pragma unroll
    for (int i = 0; i < 4; i++)
        #pragma unroll
        for (int j = 0; j < 4; j++)
            #pragma unroll
            for (int r = 0; r < 4; r++) acc[i][j][r] = 0.f;

    for (int k0 = 0; k0 < K; k0 += 64) {
        __syncthreads();
        #pragma unroll
        for (int it = 0; it < 4; it++) {
            int idx = tid + (it << 8);
            int row = idx >> 3, seg = idx & 7;
            int wb = row * 128 + ((seg << 4) ^ ((row & 7) << 4));
            float4 av = *(const float4*)(A + (size_t)(bm + row) * lda + k0 + (seg << 3));
            *(float4*)((char*)As + wb) = av;
            int col = bn + row;
            float4 bv = make_float4(0.f,0.f,0.f,0.f);
            if (col < N) bv = *(const float4*)(Bt + (size_t)col * K + k0 + (seg << 3));
            *(float4*)((char*)Bs + wb) = bv;
        }
        __syncthreads();
        #pragma unroll
        for (int ks = 0; ks < 2; ks++) {
            bf16x8 af[4], bfr[4];
            #pragma unroll
            for (int i = 0; i < 4; i++)
                af[i] = lds_frag(As, (wr<<6) + (i<<4) + l16, (ks<<6) + (g<<4));
            #pragma unroll
            for (int j = 0; j < 4; j++)
                bfr[j] = lds_frag(Bs, (wc<<6) + (j<<4) + l16, (ks<<6) + (g<<4));
            #pragma unroll
            for (int i = 0; i < 4; i++)
                #pragma unroll
                for (int j = 0; j < 4; j++)
                    acc[i][j] = __builtin_amdgcn_mfma_f32_16x16x32_bf16(af[i], bfr[j], acc[i][j], 0, 0, 0);
        }
    }
    const float bn_s = 0.99999500003749968f;
    #pragma unroll
    for (int i = 0; i < 4; i++) {
        int m = bm + (wr<<6) + (i<<4) + (g<<2);
        #pragma unroll
        for (int j = 0; j < 4; j++) {
            int c = bn + (wc<<6) + (j<<4) + l16;
            if (c >= N) continue;
            float bi = (EPI != EPI_NONE) ? bias[c] : 0.f;
            float sc = 1.f, bb = 0.f;
            if (EPI == EPI_BN_RELU) { sc = bn_g[c] * bn_s; bb = bn_b[c]; }
            #pragma unroll
            for (int r = 0; r < 4; r++) {
                float t = acc[i][j][r] + bi;
                if (EPI == EPI_BN_RELU) t = fmaxf(t * sc + bb, 0.f);
                if (OBF16) ((__hip_bfloat16*)Cv)[(size_t)(m+r)*ldc + c] = __float2bfloat16(t);
                else       ((float*)Cv)[(size_t)(m+r)*ldc + c] = t;
            }
        }
    }
}

// ================= kv GEMM (bf16 MFMA): K row-major + V transposed out =================
// A = kvin bf16 [4096][256], Bt = wkvT bf16 [512][256]. Grid (4,32).
__launch_bounds__(256)
__global__ void gemm_kv_mfma(const __hip_bfloat16* __restrict__ A,
                             const __hip_bfloat16* __restrict__ Bt,
                             __hip_bfloat16* __restrict__ kbo,   // [16][1024][64]
                             __hip_bfloat16* __restrict__ vto,   // [16][64][1024]
                             const float* __restrict__ bias)
{
    __shared__ unsigned short As[8192];
    __shared__ unsigned short Bs[8192];
    const int tid = threadIdx.x;
    const int lane = tid & 63, wv = tid >> 6;
    const int g = lane >> 4, l16 = lane & 15;
    const int wr = wv >> 1, wc = wv & 1;
    const int bm = blockIdx.y << 7;
    const int bn = blockIdx.x << 7;
    f32x4 acc[4][4];
    #pragma unroll
    for (int i = 0; i < 4; i++)
        #pragma unroll
        for (int j = 0; j < 4; j++)
            #pragma unroll
            for (int r = 0; r < 4; r++) acc[i][j][r] = 0.f;

    for (int k0 = 0; k0 < 256; k0 += 64) {
        __syncthreads();
        #pragma unroll
        for (int it = 0; it < 4; it++) {
            int idx = tid + (it << 8);
            int row = idx >> 3, seg = idx & 7;
            int wb = row * 128 + ((seg << 4) ^ ((row & 7) << 4));
            float4 av = *(const float4*)(A + (size_t)(bm + row) * 256 + k0 + (seg << 3));
            *(float4*)((char*)As + wb) = av;
            float4 bv = *(const float4*)(Bt + (size_t)(bn + row) * 256 + k0 + (seg << 3));
            *(float4*)((char*)Bs + wb) = bv;
        }
        __syncthreads();
        #pragma unroll
        for (int ks = 0; ks < 2; ks++) {
            bf16x8 af[4], bfr[4];
            #pragma unroll
            for (int i = 0; i < 4; i++)
                af[i] = lds_frag(As, (wr<<6) + (i<<4) + l16, (ks<<6) + (g<<4));
            #pragma unroll
            for (int j = 0; j < 4; j++)
                bfr[j] = lds_frag(Bs, (wc<<6) + (j<<4) + l16, (ks<<6) + (g<<4));
            #pragma unroll
            for (int i = 0; i < 4; i++)
                #pragma unroll
                for (int j = 0; j < 4; j++)
                    acc[i][j] = __builtin_amdgcn_mfma_f32_16x16x32_bf16(af[i], bfr[j], acc[i][j], 0, 0, 0);
        }
    }
    #pragma unroll
    for (int i = 0; i < 4; i++) {
        int m = bm + (wr<<6) + (i<<4) + (g<<2);
        int bimg = m >> 10, tkn0 = m & 1023;
        #pragma unroll
        for (int j = 0; j < 4; j++) {
            int c = bn + (wc<<6) + (j<<4) + l16;
            if (c < 256) {          // K: [bh][token][d]
                int wh = c >> 6, d0 = c & 63;
                __hip_bfloat16* kp = kbo + (((size_t)((bimg<<2)+wh)) << 16) + (size_t)tkn0*64 + d0;
                #pragma unroll
                for (int r = 0; r < 4; r++)
                    kp[r*64] = __float2bfloat16(acc[i][j][r] + bias[c]);
            } else {                // V: [bh][d][token], 4 contiguous tokens -> ushort4
                int c2 = c - 256;
                int wh = c2 >> 6, d = c2 & 63;
                float bi = bias[256 + c2];
                ushort4 h;
                h.x = f2bf(acc[i][j][0] + bi);
                h.y = f2bf(acc[i][j][1] + bi);
                h.z = f2bf(acc[i][j][2] + bi);
                h.w = f2bf(acc[i][j][3] + bi);
                *(ushort4*)(vto + (((size_t)((bimg<<2)+wh)) << 16) + (size_t)d*1024 + tkn0) = h;
            }
        }
    }
}

// ================= fused wproj GEMM: [ow | x_idwt] @ wprojT + b =================
// A1 = ow bf16 [16384][256] (k<256), A2 = xidwt bf16 [16384][64] (k>=256). K=320.
__launch_bounds__(256)
__global__ void gemm_wproj(const __hip_bfloat16* __restrict__ A1,
                           const __hip_bfloat16* __restrict__ A2,
                           const __hip_bfloat16* __restrict__ Bt,  // [256][320]
                           float* __restrict__ C,                  // out+256, ldc=512
                           const float* __restrict__ bias)
{
    __shared__ unsigned short As[8192];
    __shared__ unsigned short Bs[8192];
    const int tid = threadIdx.x;
    const int lane = tid & 63, wv = tid >> 6;
    const int g = lane >> 4, l16 = lane & 15;
    const int wr = wv >> 1, wc = wv & 1;
    const int bm = blockIdx.y << 7;
    const int bn = blockIdx.x << 7;
    f32x4 acc[4][4];
    #pragma unroll
    for (int i = 0; i < 4; i++)
        #pragma unroll
        for (int j = 0; j < 4; j++)
            #pragma unroll
            for (int r = 0; r < 4; r++) acc[i][j][r] = 0.f;

    for (int k0 = 0; k0 < 320; k0 += 64) {
        __syncthreads();
        #pragma unroll
        for (int it = 0; it < 4; it++) {
            int idx = tid + (it << 8);
            int row = idx >> 3, seg = idx & 7;
            int wb = row * 128 + ((seg << 4) ^ ((row & 7) << 4));
            float4 av;
            if (k0 < 256)
                av = *(const float4*)(A1 + (size_t)(bm + row) * 256 + k0 + (seg << 3));
            else
                av = *(const float4*)(A2 + (size_t)(bm + row) * 64 + (k0 - 256) + (seg << 3));
            *(float4*)((char*)As + wb) = av;
            float4 bv = *(const float4*)(Bt + (size_t)(bn + row) * 320 + k0 + (seg << 3));
            *(float4*)((char*)Bs + wb) = bv;
        }
        __syncthreads();
        #pragma unroll
        for (int ks = 0; ks < 2; ks++) {
            bf16x8 af[4], bfr[4];
            #pragma unroll
            for (int i = 0; i < 4; i++)
                af[i] = lds_frag(As, (wr<<6) + (i<<4) + l16, (ks<<6) + (g<<4));
            #pragma unroll
            for (int j = 0; j < 4; j++)
                bfr[j] = lds_frag(Bs, (wc<<6) + (j<<4) + l16, (ks<<6) + (g<<4));
            #pragma unroll
            for (int i = 0; i < 4; i++)
                #pragma unroll
                for (int j = 0; j < 4; j++)
                    acc[i][j] = __builtin_amdgcn_mfma_f32_16x16x32_bf16(af[i], bfr[j], acc[i][j], 0, 0, 0);
        }
    }
    #pragma unroll
    for (int i = 0; i < 4; i++) {
        int m = bm + (wr<<6) + (i<<4) + (g<<2);
        #pragma unroll
        for (int j = 0; j < 4; j++) {
            int c = bn + (wc<<6) + (j<<4) + l16;
            float bi = bias[c];
            #pragma unroll
            for (int r = 0; r < 4; r++)
                C[(size_t)(m+r)*512 + c] = acc[i][j][r] + bi;
        }
    }
}

// ================= 3x3 conv: bf16 MFMA implicit-im2col =================
__launch_bounds__(256)
__global__ void conv3_mfma(const __hip_bfloat16* __restrict__ Xd,
                           const __hip_bfloat16* __restrict__ Wt,
                           float* __restrict__ C,
                           const float* __restrict__ bias,
                           const float* __restrict__ bn_g,
                           const float* __restrict__ bn_b)
{
    __shared__ unsigned short As[8192];
    __shared__ unsigned short Bs[8192];
    const int tid = threadIdx.x;
    const int lane = tid & 63, wv = tid >> 6;
    const int g = lane >> 4, l16 = lane & 15;
    const int wr = wv >> 1, wc = wv & 1;
    const int bm = blockIdx.y << 7;
    const int bn = blockIdx.x << 7;
    f32x4 acc[4][4];
    #pragma unroll
    for (int i = 0; i < 4; i++)
        #pragma unroll
        for (int j = 0; j < 4; j++)
            #pragma unroll
            for (int r = 0; r < 4; r++) acc[i][j][r] = 0.f;

    for (int k0 = 0; k0 < 2304; k0 += 64) {
        int tap = k0 >> 8;
        int dy = tap / 3 - 1;
        int dx = tap - (tap / 3) * 3 - 1;
        int i0 = k0 & 255;
        __syncthreads();
        #pragma unroll
        for (int it = 0; it < 4; it++) {
            int idx = tid + (it << 8);
            int row = idx >> 3, seg = idx & 7;
            int wb = row * 128 + ((seg << 4) ^ ((row & 7) << 4));
            int m = bm + row;
            int bimg = m >> 10, s = m & 1023;
            int y = (s >> 5) + dy, xx = (s & 31) + dx;
            float4 av = make_float4(0.f,0.f,0.f,0.f);
            if ((unsigned)y < 32u && (unsigned)xx < 32u)
                av = *(const float4*)(Xd + ((((bimg<<10) + (y<<5) + xx)) << 8) + i0 + (seg<<3));
            *(float4*)((char*)As + wb) = av;
            float4 bv = *(const float4*)(Wt + (size_t)(bn + row) * 2304 + k0 + (seg<<3));
            *(float4*)((char*)Bs + wb) = bv;
        }
        __syncthreads();
        #pragma unroll
        for (int ks = 0; ks < 2; ks++) {
            bf16x8 af[4], bfr[4];
            #pragma unroll
            for (int i = 0; i < 4; i++)
                af[i] = lds_frag(As, (wr<<6) + (i<<4) + l16, (ks<<6) + (g<<4));
            #pragma unroll
            for (int j = 0; j < 4; j++)
                bfr[j] = lds_frag(Bs, (wc<<6) + (j<<4) + l16, (ks<<6) + (g<<4));
            #pragma unroll
            for (int i = 0; i < 4; i++)
                #pragma unroll
                for (int j = 0; j < 4; j++)
                    acc[i][j] = __builtin_amdgcn_mfma_f32_16x16x32_bf16(af[i], bfr[j], acc[i][j], 0, 0, 0);
        }
    }
    const float bn_s = 0.99999500003749968f;
    #pragma unroll
    for (int i = 0; i < 4; i++) {
        int m = bm + (wr<<6) + (i<<4) + (g<<2);
        #pragma unroll
        for (int j = 0; j < 4; j++) {
            int c = bn + (wc<<6) + (j<<4) + l16;
            float sc = bn_g[c] * bn_s, bb = bn_b[c], bi = bias[c];
            #pragma unroll
            for (int r = 0; r < 4; r++)
                C[(size_t)(m + r) * 256 + c] = fmaxf((acc[i][j][r] + bi) * sc + bb, 0.f);
        }
    }
}

// ================= small prep kernels =================
// weight transpose + cvt: in fp32 [K][N] -> out bf16 [N][K]
__global__ void wtrans(const float* __restrict__ in, __hip_bfloat16* __restrict__ o,
                       int K, int N)
{
    int idx = blockIdx.x * 256 + threadIdx.x;
    if (idx >= K * N) return;
    int n = idx / K, k = idx - n * K;
    o[idx] = __float2bfloat16(in[(size_t)k * N + n]);
}

// conv filter: Wf [o][i][tap] fp32 -> Wt bf16 [o][tap*256+i]
__global__ void wt_kernel(const float* __restrict__ Wf, __hip_bfloat16* __restrict__ Wt)
{
    int o = blockIdx.x;
    int i = threadIdx.x;
    const float* src = Wf + (size_t)(o * 256 + i) * 9;
    __hip_bfloat16* dst = Wt + (size_t)o * 2304 + i;
    #pragma unroll
    for (int tap = 0; tap < 9; tap++)
        dst[tap * 256] = __float2bfloat16(src[tap]);
}

// fp32 -> bf16, 4 elements/thread
__global__ void cvt_bf16(const float* __restrict__ in, __hip_bfloat16* __restrict__ o)
{
    int i = blockIdx.x * 256 + threadIdx.x;
    float4 v = ((const float4*)in)[i];
    ushort4 h;
    h.x = f2bf(v.x); h.y = f2bf(v.y); h.z = f2bf(v.z); h.w = f2bf(v.w);
    *(ushort4*)(o + (size_t)i * 4) = h;
}

// ================= window attention (bf16 in/out) =================
__launch_bounds__(256)
__global__ void win_attn(const __hip_bfloat16* __restrict__ qkv,
                         __hip_bfloat16* __restrict__ sa_o)
{
    int gw = blockIdx.x * 4 + (threadIdx.x >> 6);
    int lane = threadIdx.x & 63;
    int b  = gw >> 12;
    int g  = (gw >> 2) & 1023;
    int sh = gw & 3;
    int hg = g >> 5, wg = g & 31;
    float q[4], k[4], v[4];
    int rows[4];
    #pragma unroll
    for (int l = 0; l < 4; l++) {
        int h = (hg << 1) + (l >> 1), w = (wg << 1) + (l & 1);
        int row = (b << 12) + (h << 6) + w;
        rows[l] = row;
        const __hip_bfloat16* p = qkv + (size_t)row * 768 + sh * 64 + lane;
        q[l] = __bfloat162float(p[0]);
        k[l] = __bfloat162float(p[256]);
        v[l] = __bfloat162float(p[512]);
    }
    float s[4][4];
    #pragma unroll
    for (int l = 0; l < 4; l++)
        #pragma unroll
        for (int m = 0; m < 4; m++) s[l][m] = q[l] * k[m];
    #pragma unroll
    for (int off = 32; off > 0; off >>= 1)
        #pragma unroll
        for (int l = 0; l < 4; l++)
            #pragma unroll
            for (int m = 0; m < 4; m++)
                s[l][m] += __shfl_xor(s[l][m], off, 64);
    #pragma unroll
    for (int l = 0; l < 4; l++) {
        float s0 = s[l][0]*WSCALE, s1 = s[l][1]*WSCALE, s2 = s[l][2]*WSCALE, s3 = s[l][3]*WSCALE;
        float mx = fmaxf(fmaxf(s0,s1), fmaxf(s2,s3));
        float p0 = __expf(s0-mx), p1 = __expf(s1-mx), p2 = __expf(s2-mx), p3 = __expf(s3-mx);
        float inv = 1.f / (p0+p1+p2+p3);
        float o = (p0*v[0] + p1*v[1] + p2*v[2] + p3*v[3]) * inv;
        sa_o[(size_t)rows[l] * 256 + sh * 64 + lane] = __float2bfloat16(o);
    }
}

// ================= Haar DWT (fp32 in -> bf16 channel-last) =================
__global__ void dwt_kernel(const float* __restrict__ r, __hip_bfloat16* __restrict__ xd)
{
    int t = blockIdx.x * 256 + threadIdx.x;
    int o = t & 63;
    int x = (t >> 6) & 31;
    int y = (t >> 11) & 31;
    int b = t >> 16;
    const float* rb = r + (b << 18);
    int base = ((y << 1) << 6) + (x << 1);
    float a  = rb[(base     ) * 64 + o];
    float bb = rb[(base +  1) * 64 + o];
    float c  = rb[(base + 64) * 64 + o];
    float d  = rb[(base + 65) * 64 + o];
    float ll = 0.5f*(a+bb+c+d), lh = 0.5f*(a+bb-c-d);
    float hl = 0.5f*(a-bb+c-d), hh = 0.5f*(a-bb-c+d);
    __hip_bfloat16* outp = xd + (((b << 10) + (y << 5) + x) << 8) + o;
    outp[0]   = __float2bfloat16(ll);
    outp[64]  = __float2bfloat16(lh);
    outp[128] = __float2bfloat16(hl);
    outp[192] = __float2bfloat16(hh);
}

// ================= Haar IDWT (fp32 in -> bf16 out) =================
__global__ void idwt_kernel(const float* __restrict__ xd, __hip_bfloat16* __restrict__ xi)
{
    int t = blockIdx.x * 256 + threadIdx.x;
    int o = t & 63;
    int x = (t >> 6) & 31;
    int y = (t >> 11) & 31;
    int b = t >> 16;
    const float* p = xd + (((b << 10) + (y << 5) + x) << 8);
    float ll = p[o], lh = p[64+o], hl = p[128+o], hh = p[192+o];
    float y00 = 0.5f*(ll+lh+hl+hh);
    float y01 = 0.5f*(ll+lh-hl-hh);
    float y10 = 0.5f*(ll-lh+hl-hh);
    float y11 = 0.5f*(ll-lh-hl+hh);
    __hip_bfloat16* ob = xi + ((size_t)b << 18);
    int base = ((y << 1) << 6) + (x << 1);
    ob[(size_t)(base     ) * 64 + o] = __float2bfloat16(y00);
    ob[(size_t)(base +  1) * 64 + o] = __float2bfloat16(y01);
    ob[(size_t)(base + 64) * 64 + o] = __float2bfloat16(y10);
    ob[(size_t)(base + 65) * 64 + o] = __float2bfloat16(y11);
}

// ================= LayerNorm over 256 (fp32 in -> bf16 out) =================
__launch_bounds__(256)
__global__ void ln_kernel(const float* __restrict__ X, const float* __restrict__ g,
                          const float* __restrict__ bta, __hip_bfloat16* __restrict__ Y)
{
    int row = blockIdx.x;
    int t = threadIdx.x;
    float x = X[(size_t)row * 256 + t];
    __shared__ float red[4];
    int wv = t >> 6, ln = t & 63;
    float s = x;
    #pragma unroll
    for (int off = 32; off > 0; off >>= 1) s += __shfl_xor(s, off, 64);
    if (ln == 0) red[wv] = s;
    __syncthreads();
    float m = (red[0]+red[1]+red[2]+red[3]) * (1.f/256.f);
    float d = x - m;
    float s2 = d * d;
    #pragma unroll
    for (int off = 32; off > 0; off >>= 1) s2 += __shfl_xor(s2, off, 64);
    __syncthreads();
    if (ln == 0) red[wv] = s2;
    __syncthreads();
    float var = (red[0]+red[1]+red[2]+red[3]) * (1.f/256.f);
    float inv = 1.f / sqrtf(var + WEPS);
    Y[(size_t)row * 256 + t] = __float2bfloat16(d * inv * g[t] + bta[t]);
}

// ================= MFMA flash attention (bf16 out) =================
__launch_bounds__(256)
__global__ void flash_mfma(const __hip_bfloat16* __restrict__ qb,
                           const __hip_bfloat16* __restrict__ kb,
                           const __hip_bfloat16* __restrict__ vt,
                           __hip_bfloat16* __restrict__ ow)
{
    __shared__ unsigned short Ks[4096];
    __shared__ unsigned short Vs[4096];
    const int tid = threadIdx.x;
    const int wv = tid >> 6;
    const int lane = tid & 63;
    const int g = lane >> 4, q16 = lane & 15;
    const int bh = blockIdx.y;
    const int b = bh >> 2, wh = bh & 3;
    const int qbase = (blockIdx.x << 6) + (wv << 4);

    const __hip_bfloat16* qp = qb + ((size_t)((b << 12) + qbase + q16)) * 256 + wh * 64 + g * 8;
    bf16x8 qf0 = *(const bf16x8*)qp;
    bf16x8 qf1 = *(const bf16x8*)(qp + 32);

    const __hip_bfloat16* kbase = kb + ((size_t)bh << 16);
    const __hip_bfloat16* vbase = vt + ((size_t)bh << 16);

    f32x4 oacc[4];
    #pragma unroll
    for (int dc = 0; dc < 4; dc++)
        #pragma unroll
        for (int r = 0; r < 4; r++) oacc[dc][r] = 0.f;
    float m_old = -1e30f, lsum = 0.f;

    for (int t0 = 0; t0 < 1024; t0 += 64) {
        __syncthreads();
        #pragma unroll
        for (int it = 0; it < 2; it++) {
            int off = (tid << 4) + (it << 12);
            int row = off >> 7;
            int inner = off & 127;
            int wb = row * 128 + (inner ^ ((row & 7) << 4));
            float4 kd = *(const float4*)(kbase + (t0 + row) * 64 + (inner >> 1));
            float4 vd = *(const float4*)(vbase + row * 1024 + t0 + (inner >> 1));
            *(float4*)((char*)Ks + wb) = kd;
            *(float4*)((char*)Vs + wb) = vd;
        }
        __syncthreads();

        f32x4 st[4];
        #pragma unroll
        for (int sub = 0; sub < 4; sub++) {
            #pragma unroll
            for (int r = 0; r < 4; r++) st[sub][r] = 0.f;
            bf16x8 k0 = lds_frag(Ks, sub * 16 + q16, g * 16);
            bf16x8 k1 = lds_frag(Ks, sub * 16 + q16, 64 + g * 16);
            st[sub] = __builtin_amdgcn_mfma_f32_16x16x32_bf16(k0, qf0, st[sub], 0, 0, 0);
            st[sub] = __builtin_amdgcn_mfma_f32_16x16x32_bf16(k1, qf1, st[sub], 0, 0, 0);
        }

        float mx = -1e30f;
        float s[4][4];
        #pragma unroll
        for (int t = 0; t < 4; t++)
            #pragma unroll
            for (int r = 0; r < 4; r++) {
                float v = st[t][r] * WSCALE;
                s[t][r] = v;
                mx = fmaxf(mx, v);
            }
        mx = fmaxf(mx, __shfl_xor(mx, 16, 64));
        mx = fmaxf(mx, __shfl_xor(mx, 32, 64));
        float m_new = fmaxf(m_old, mx);
        float alpha = __expf(m_old - m_new);
        float psum = 0.f;
        unsigned pk[4][2];
        #pragma unroll
        for (int t = 0; t < 4; t++) {
            float p0 = __expf(s[t][0] - m_new), p1 = __expf(s[t][1] - m_new);
            float p2 = __expf(s[t][2] - m_new), p3 = __expf(s[t][3] - m_new);
            psum += (p0 + p1) + (p2 + p3);
            pk[t][0] = pack2bf(p0, p1);
            pk[t][1] = pack2bf(p2, p3);
        }
        psum += __shfl_xor(psum, 16, 64);
        psum += __shfl_xor(psum, 32, 64);
        lsum = lsum * alpha + psum;
        m_old = m_new;

        #pragma unroll
        for (int r = 0; r < 4; r++) {
            float sc = __shfl(alpha, (g << 2) + r, 64);
            #pragma unroll
            for (int dc = 0; dc < 4; dc++) oacc[dc][r] *= sc;
        }

        bool ghi = (g & 2) != 0;
        unsigned pkA0[2], pkA1[2];
        pkA0[0] = ghi ? pk[1][0] : pk[0][0];
        pkA0[1] = ghi ? pk[1][1] : pk[0][1];
        pkA1[0] = ghi ? pk[3][0] : pk[2][0];
        pkA1[1] = ghi ? pk[3][1] : pk[2][1];
        union { int u[4]; bf16x8 v; } A0, A1;
        #pragma unroll
        for (int c = 0; c < 4; c++) {
            int src = (((2 * g + (c >> 1)) & 3) << 4) | q16;
            A0.u[c] = __shfl((int)pkA0[c & 1], src, 64);
            A1.u[c] = __shfl((int)pkA1[c & 1], src, 64);
        }

        #pragma unroll
        for (int dc = 0; dc < 4; dc++) {
            bf16x8 v0 = lds_frag(Vs, dc * 16 + q16, g * 16);
            bf16x8 v1 = lds_frag(Vs, dc * 16 + q16, 64 + g * 16);
            oacc[dc] = __builtin_amdgcn_mfma_f32_16x16x32_bf16(A0.v, v0, oacc[dc], 0, 0, 0);
            oacc[dc] = __builtin_amdgcn_mfma_f32_16x16x32_bf16(A1.v, v1, oacc[dc], 0, 0, 0);
        }
    }

    #pragma unroll
    for (int r = 0; r < 4; r++) {
        float inv = 1.f / __shfl(lsum, (g << 2) + r, 64);
        int qrow = (b << 12) + qbase + (g << 2) + r;
        #pragma unroll
        for (int dc = 0; dc < 4; dc++)
            ow[(size_t)qrow * 256 + wh * 64 + dc * 16 + q16] =
                __float2bfloat16(oacc[dc][r] * inv);
    }
}

extern "C" void kernel_launch(void* const* d_in, const int* in_sizes, int n_in,
                              void* d_out, int out_size, void* d_ws, size_t ws_size,
                              hipStream_t stream)
{
    const float* x        = (const float*)d_in[0];
    const float* wq_w     = (const float*)d_in[1];
    const float* kv_ln_g  = (const float*)d_in[2];
    const float* kv_ln_b  = (const float*)d_in[3];
    const float* wkv_w    = (const float*)d_in[4];
    const float* wkv_b    = (const float*)d_in[5];
    const float* wproj_w  = (const float*)d_in[6];
    const float* wproj_b  = (const float*)d_in[7];
    const float* reduce_w = (const float*)d_in[8];
    const float* reduce_b = (const float*)d_in[9];
    const float* rbn_g    = (const float*)d_in[10];
    const float* rbn_b    = (const float*)d_in[11];
    const float* filter_w = (const float*)d_in[12];
    const float* filter_b = (const float*)d_in[13];
    const float* fbn_g    = (const float*)d_in[14];
    const float* fbn_b    = (const float*)d_in[15];
    const float* sqkv_w   = (const float*)d_in[16];
    const float* sproj_w  = (const float*)d_in[17];
    const float* sproj_b  = (const float*)d_in[18];
    float* out = (float*)d_out;
    float* ws  = (float*)d_ws;

    // workspace layout (float units)
    __hip_bfloat16* qkvb  = (__hip_bfloat16*)(ws);             // 12,582,912 bf16 (6,291,456 f)
    __hip_bfloat16* owb   = (__hip_bfloat16*)(ws);             // reuse after win_attn
    __hip_bfloat16* sa_ob = (__hip_bfloat16*)(ws + 6291456);   // 4,194,304 bf16
    __hip_bfloat16* xb    = (__hip_bfloat16*)(ws + 8388608);   // 8,388,608 bf16
    __hip_bfloat16* sqkvT = (__hip_bfloat16*)(ws + 12582912);  // 393,216 bf16
    __hip_bfloat16* wqT   = (__hip_bfloat16*)(ws + 12779520);  // 131,072 bf16
    __hip_bfloat16* redT  = (__hip_bfloat16*)(ws + 12845056);  // 32,768 bf16
    __hip_bfloat16* sprojT= (__hip_bfloat16*)(ws + 12861440);  // 65,536 bf16
    __hip_bfloat16* wkvT  = (__hip_bfloat16*)(ws + 12894208);  // 131,072 bf16
    __hip_bfloat16* wprojT= (__hip_bfloat16*)(ws + 13025280);  // 81,920 bf16
    __hip_bfloat16* wt2b  = (__hip_bfloat16*)(ws + 13066240);  // 589,824 bf16
    float* rbuf  = ws + 13361152;                              // 1,048,576 f
    __hip_bfloat16* xd1b  = (__hip_bfloat16*)(ws + 14409728);  // 1,048,576 bf16
    float* xd2   = ws + 14934016;                              // 1,048,576 f
    __hip_bfloat16* kvinb = (__hip_bfloat16*)(ws + 15982592);  // 1,048,576 bf16
    __hip_bfloat16* xidwtb= (__hip_bfloat16*)(ws + 16506880);  // 1,048,576 bf16
    __hip_bfloat16* qbw   = (__hip_bfloat16*)(ws + 17031168);  // 4,194,304 bf16
    __hip_bfloat16* kbb   = (__hip_bfloat16*)(ws + 19128320);  // 1,048,576 bf16
    __hip_bfloat16* vtb   = (__hip_bfloat16*)(ws + 19652608);  // 1,048,576 bf16

    dim3 blk(256);

    // prep: x -> bf16, weight transposes
    cvt_bf16<<<dim3(8192), blk, 0, stream>>>(x, xb);
    wtrans<<<dim3(1536), blk, 0, stream>>>(sqkv_w, sqkvT, 512, 768);
    wtrans<<<dim3(512),  blk, 0, stream>>>(wq_w, wqT, 512, 256);
    wtrans<<<dim3(128),  blk, 0, stream>>>(reduce_w, redT, 512, 64);
    wtrans<<<dim3(256),  blk, 0, stream>>>(sproj_w, sprojT, 256, 256);
    wtrans<<<dim3(512),  blk, 0, stream>>>(wkv_w, wkvT, 256, 512);
    wtrans<<<dim3(320),  blk, 0, stream>>>(wproj_w, wprojT, 320, 256);
    wt_kernel<<<dim3(256), blk, 0, stream>>>(filter_w, wt2b);

    // 1. qkv = xb @ sqkv_w  (bf16 out)
    gemm_bf16<EPI_NONE,1><<<dim3(6,128), blk, 0, stream>>>(xb, 512, sqkvT, 512, qkvb, 768,
                                                           768, nullptr, nullptr, nullptr);
    // 2. window attention (bf16 -> bf16)
    win_attn<<<dim3(4096), blk, 0, stream>>>(qkvb, sa_ob);
    // 3. sa_out -> out cols [0,256)
    gemm_bf16<EPI_BIAS,0><<<dim3(2,128), blk, 0, stream>>>(sa_ob, 256, sprojT, 256, out, 512,
                                                           256, sproj_b, nullptr, nullptr);
    // 4. qw = xb @ wq_w (bf16 out)
    gemm_bf16<EPI_NONE,1><<<dim3(2,128), blk, 0, stream>>>(xb, 512, wqT, 512, qbw, 256,
                                                           256, nullptr, nullptr, nullptr);
    // 5. r = relu(bn(xb @ reduce_w + b))  (fp32 out, N=64)
    gemm_bf16<EPI_BN_RELU,0><<<dim3(1,128), blk, 0, stream>>>(xb, 512, redT, 512, rbuf, 64,
                                                              64, reduce_b, rbn_g, rbn_b);
    // 6. DWT -> bf16
    dwt_kernel<<<dim3(1024), blk, 0, stream>>>(rbuf, xd1b);
    // 7. 3x3 conv MFMA + BN + ReLU -> fp32 xd2
    conv3_mfma<<<dim3(2,32), blk, 0, stream>>>(xd1b, wt2b, xd2, filter_b, fbn_g, fbn_b);
    // 8. layernorm -> bf16
    ln_kernel<<<dim3(4096), blk, 0, stream>>>(xd2, kv_ln_g, kv_ln_b, kvinb);
    // 9. kv GEMM -> bf16 K + transposed V
    gemm_kv_mfma<<<dim3(4,32), blk, 0, stream>>>(kvinb, wkvT, kbb, vtb, wkv_b);
    // 10. IDWT -> bf16
    idwt_kernel<<<dim3(1024), blk, 0, stream>>>(xd2, xidwtb);
    // 11. flash attention -> bf16 ow (reuses qkvb space)
    flash_mfma<<<dim3(64,16), blk, 0, stream>>>(qbw, kbb, vtb, owb);
    // 12. fused wproj: [ow | x_idwt] @ wproj + b -> out cols [256,512)
    gemm_wproj<<<dim3(2,128), blk, 0, stream>>>(owb, xidwtb, wprojT, out + 256, wproj_b);
}

// Round 5
// 216.885 us; speedup vs baseline: 7.5264x; 1.2191x over previous
//
#include <hip/hip_runtime.h>
#include <hip/hip_bf16.h>
#include <math.h>

#define WEPS 1e-5f
#define WSCALE 0.125f

enum { EPI_NONE=0, EPI_BIAS=1, EPI_BN_RELU=2 };

typedef __attribute__((ext_vector_type(8))) short bf16x8;
typedef __attribute__((ext_vector_type(4))) float f32x4;

static __device__ inline unsigned short f2bf(float f) {
    __hip_bfloat16 h = __float2bfloat16(f);
    return *(unsigned short*)&h;
}
static __device__ inline unsigned pack2bf(float a, float b) {
    return (unsigned)f2bf(a) | ((unsigned)f2bf(b) << 16);
}

// swizzled LDS 16B fragment read: 128B rows, byte ^= (row&7)<<4
static __device__ inline bf16x8 lds_frag(const unsigned short* base, int row, int inner) {
    int byte = row * 128 + (inner ^ ((row & 7) << 4));
    return *(const bf16x8*)((const char*)base + byte);
}
// swizzled LDS 16B fragment read: 256B rows, byte ^= (row&15)<<4
static __device__ inline bf16x8 lds_frag256(const unsigned short* base, int row, int inner) {
    int byte = row * 256 + (inner ^ ((row & 15) << 4));
    return *(const bf16x8*)((const char*)base + byte);
}

// ================= bf16 MFMA GEMM template =================
// C[M,N] = A[M,K](bf16,row-major) @ Bt[N,K](bf16)^T. 128x128 tile, BK=64,
// 4 waves x 64x64. M mult 128, K mult 64; N col-guarded.
template<int EPI, int OBF16>
__launch_bounds__(256)
__global__ void gemm_bf16(const __hip_bfloat16* __restrict__ A, int lda,
                          const __hip_bfloat16* __restrict__ Bt, int K,
                          void* __restrict__ Cv, int ldc, int N,
                          const float* __restrict__ bias,
                          const float* __restrict__ bn_g,
                          const float* __restrict__ bn_b)
{
    __shared__ unsigned short As[8192];
    __shared__ unsigned short Bs[8192];
    const int tid = threadIdx.x;
    const int lane = tid & 63, wv = tid >> 6;
    const int g = lane >> 4, l16 = lane & 15;
    const int wr = wv >> 1, wc = wv & 1;
    const int bm = blockIdx.y << 7;
    const int bn = blockIdx.x << 7;
    f32x4 acc[4][4];
    #pragma unroll
    for (int i = 0; i < 4; i++)
        #pragma unroll
        for (int j = 0; j < 4; j++)
            #pragma unroll
            for (int r = 0; r < 4; r++) acc[i][j][r] = 0.f;

    for (int k0 = 0; k0 < K; k0 += 64) {
        __syncthreads();
        #pragma unroll
        for (int it = 0; it < 4; it++) {
            int idx = tid + (it << 8);
            int row = idx >> 3, seg = idx & 7;
            int wb = row * 128 + ((seg << 4) ^ ((row & 7) << 4));
            float4 av = *(const float4*)(A + (size_t)(bm + row) * lda + k0 + (seg << 3));
            *(float4*)((char*)As + wb) = av;
            int col = bn + row;
            float4 bv = make_float4(0.f,0.f,0.f,0.f);
            if (col < N) bv = *(const float4*)(Bt + (size_t)col * K + k0 + (seg << 3));
            *(float4*)((char*)Bs + wb) = bv;
        }
        __syncthreads();
        #pragma unroll
        for (int ks = 0; ks < 2; ks++) {
            bf16x8 af[4], bfr[4];
            #pragma unroll
            for (int i = 0; i < 4; i++)
                af[i] = lds_frag(As, (wr<<6) + (i<<4) + l16, (ks<<6) + (g<<4));
            #pragma unroll
            for (int j = 0; j < 4; j++)
                bfr[j] = lds_frag(Bs, (wc<<6) + (j<<4) + l16, (ks<<6) + (g<<4));
            #pragma unroll
            for (int i = 0; i < 4; i++)
                #pragma unroll
                for (int j = 0; j < 4; j++)
                    acc[i][j] = __builtin_amdgcn_mfma_f32_16x16x32_bf16(af[i], bfr[j], acc[i][j], 0, 0, 0);
        }
    }
    const float bn_s = 0.99999500003749968f;
    #pragma unroll
    for (int i = 0; i < 4; i++) {
        int m = bm + (wr<<6) + (i<<4) + (g<<2);
        #pragma unroll
        for (int j = 0; j < 4; j++) {
            int c = bn + (wc<<6) + (j<<4) + l16;
            if (c >= N) continue;
            float bi = (EPI != EPI_NONE) ? bias[c] : 0.f;
            float sc = 1.f, bb = 0.f;
            if (EPI == EPI_BN_RELU) { sc = bn_g[c] * bn_s; bb = bn_b[c]; }
            #pragma unroll
            for (int r = 0; r < 4; r++) {
                float t = acc[i][j][r] + bi;
                if (EPI == EPI_BN_RELU) t = fmaxf(t * sc + bb, 0.f);
                if (OBF16) ((__hip_bfloat16*)Cv)[(size_t)(m+r)*ldc + c] = __float2bfloat16(t);
                else       ((float*)Cv)[(size_t)(m+r)*ldc + c] = t;
            }
        }
    }
}

// ================= kv GEMM (bf16 MFMA): K row-major + V transposed out =================
__launch_bounds__(256)
__global__ void gemm_kv_mfma(const __hip_bfloat16* __restrict__ A,
                             const __hip_bfloat16* __restrict__ Bt,
                             __hip_bfloat16* __restrict__ kbo,   // [16][1024][64]
                             __hip_bfloat16* __restrict__ vto,   // [16][64][1024]
                             const float* __restrict__ bias)
{
    __shared__ unsigned short As[8192];
    __shared__ unsigned short Bs[8192];
    const int tid = threadIdx.x;
    const int lane = tid & 63, wv = tid >> 6;
    const int g = lane >> 4, l16 = lane & 15;
    const int wr = wv >> 1, wc = wv & 1;
    const int bm = blockIdx.y << 7;
    const int bn = blockIdx.x << 7;
    f32x4 acc[4][4];
    #pragma unroll
    for (int i = 0; i < 4; i++)
        #pragma unroll
        for (int j = 0; j < 4; j++)
            #pragma unroll
            for (int r = 0; r < 4; r++) acc[i][j][r] = 0.f;

    for (int k0 = 0; k0 < 256; k0 += 64) {
        __syncthreads();
        #pragma unroll
        for (int it = 0; it < 4; it++) {
            int idx = tid + (it << 8);
            int row = idx >> 3, seg = idx & 7;
            int wb = row * 128 + ((seg << 4) ^ ((row & 7) << 4));
            float4 av = *(const float4*)(A + (size_t)(bm + row) * 256 + k0 + (seg << 3));
            *(float4*)((char*)As + wb) = av;
            float4 bv = *(const float4*)(Bt + (size_t)(bn + row) * 256 + k0 + (seg << 3));
            *(float4*)((char*)Bs + wb) = bv;
        }
        __syncthreads();
        #pragma unroll
        for (int ks = 0; ks < 2; ks++) {
            bf16x8 af[4], bfr[4];
            #pragma unroll
            for (int i = 0; i < 4; i++)
                af[i] = lds_frag(As, (wr<<6) + (i<<4) + l16, (ks<<6) + (g<<4));
            #pragma unroll
            for (int j = 0; j < 4; j++)
                bfr[j] = lds_frag(Bs, (wc<<6) + (j<<4) + l16, (ks<<6) + (g<<4));
            #pragma unroll
            for (int i = 0; i < 4; i++)
                #pragma unroll
                for (int j = 0; j < 4; j++)
                    acc[i][j] = __builtin_amdgcn_mfma_f32_16x16x32_bf16(af[i], bfr[j], acc[i][j], 0, 0, 0);
        }
    }
    #pragma unroll
    for (int i = 0; i < 4; i++) {
        int m = bm + (wr<<6) + (i<<4) + (g<<2);
        int bimg = m >> 10, tkn0 = m & 1023;
        #pragma unroll
        for (int j = 0; j < 4; j++) {
            int c = bn + (wc<<6) + (j<<4) + l16;
            if (c < 256) {          // K: [bh][token][d]
                int wh = c >> 6, d0 = c & 63;
                __hip_bfloat16* kp = kbo + (((size_t)((bimg<<2)+wh)) << 16) + (size_t)tkn0*64 + d0;
                #pragma unroll
                for (int r = 0; r < 4; r++)
                    kp[r*64] = __float2bfloat16(acc[i][j][r] + bias[c]);
            } else {                // V: [bh][d][token]
                int c2 = c - 256;
                int wh = c2 >> 6, d = c2 & 63;
                float bi = bias[256 + c2];
                ushort4 h;
                h.x = f2bf(acc[i][j][0] + bi);
                h.y = f2bf(acc[i][j][1] + bi);
                h.z = f2bf(acc[i][j][2] + bi);
                h.w = f2bf(acc[i][j][3] + bi);
                *(ushort4*)(vto + (((size_t)((bimg<<2)+wh)) << 16) + (size_t)d*1024 + tkn0) = h;
            }
        }
    }
}

// ================= fused wproj GEMM: [ow | x_idwt] @ wprojT + b =================
__launch_bounds__(256)
__global__ void gemm_wproj(const __hip_bfloat16* __restrict__ A1,
                           const __hip_bfloat16* __restrict__ A2,
                           const __hip_bfloat16* __restrict__ Bt,  // [256][320]
                           float* __restrict__ C,                  // out+256, ldc=512
                           const float* __restrict__ bias)
{
    __shared__ unsigned short As[8192];
    __shared__ unsigned short Bs[8192];
    const int tid = threadIdx.x;
    const int lane = tid & 63, wv = tid >> 6;
    const int g = lane >> 4, l16 = lane & 15;
    const int wr = wv >> 1, wc = wv & 1;
    const int bm = blockIdx.y << 7;
    const int bn = blockIdx.x << 7;
    f32x4 acc[4][4];
    #pragma unroll
    for (int i = 0; i < 4; i++)
        #pragma unroll
        for (int j = 0; j < 4; j++)
            #pragma unroll
            for (int r = 0; r < 4; r++) acc[i][j][r] = 0.f;

    for (int k0 = 0; k0 < 320; k0 += 64) {
        __syncthreads();
        #pragma unroll
        for (int it = 0; it < 4; it++) {
            int idx = tid + (it << 8);
            int row = idx >> 3, seg = idx & 7;
            int wb = row * 128 + ((seg << 4) ^ ((row & 7) << 4));
            float4 av;
            if (k0 < 256)
                av = *(const float4*)(A1 + (size_t)(bm + row) * 256 + k0 + (seg << 3));
            else
                av = *(const float4*)(A2 + (size_t)(bm + row) * 64 + (k0 - 256) + (seg << 3));
            *(float4*)((char*)As + wb) = av;
            float4 bv = *(const float4*)(Bt + (size_t)(bn + row) * 320 + k0 + (seg << 3));
            *(float4*)((char*)Bs + wb) = bv;
        }
        __syncthreads();
        #pragma unroll
        for (int ks = 0; ks < 2; ks++) {
            bf16x8 af[4], bfr[4];
            #pragma unroll
            for (int i = 0; i < 4; i++)
                af[i] = lds_frag(As, (wr<<6) + (i<<4) + l16, (ks<<6) + (g<<4));
            #pragma unroll
            for (int j = 0; j < 4; j++)
                bfr[j] = lds_frag(Bs, (wc<<6) + (j<<4) + l16, (ks<<6) + (g<<4));
            #pragma unroll
            for (int i = 0; i < 4; i++)
                #pragma unroll
                for (int j = 0; j < 4; j++)
                    acc[i][j] = __builtin_amdgcn_mfma_f32_16x16x32_bf16(af[i], bfr[j], acc[i][j], 0, 0, 0);
        }
    }
    #pragma unroll
    for (int i = 0; i < 4; i++) {
        int m = bm + (wr<<6) + (i<<4) + (g<<2);
        #pragma unroll
        for (int j = 0; j < 4; j++) {
            int c = bn + (wc<<6) + (j<<4) + l16;
            float bi = bias[c];
            #pragma unroll
            for (int r = 0; r < 4; r++)
                C[(size_t)(m+r)*512 + c] = acc[i][j][r] + bi;
        }
    }
}

// ================= 3x3 conv: bf16 MFMA, 64x64 tile, BK=128, double-buffered =====
// Xd bf16 [B*1024][256] channel-last; Wt bf16 [256][2304] (k = tap*256+ci).
// Grid (4, 64): bn = blockIdx.x*64, bm = blockIdx.y*64. 18 K-iters of 128.
__launch_bounds__(256)
__global__ void conv3_mfma(const __hip_bfloat16* __restrict__ Xd,
                           const __hip_bfloat16* __restrict__ Wt,
                           float* __restrict__ C,
                           const float* __restrict__ bias,
                           const float* __restrict__ bn_g,
                           const float* __restrict__ bn_b)
{
    __shared__ unsigned short As[2][8192];   // 64 rows x 128 k, 256B rows swizzled
    __shared__ unsigned short Bs[2][8192];
    const int tid = threadIdx.x;
    const int lane = tid & 63, wv = tid >> 6;
    const int g = lane >> 4, l16 = lane & 15;
    const int wr = wv >> 1, wc = wv & 1;
    const int bm = blockIdx.y << 6;
    const int bn = blockIdx.x << 6;

    // per-thread staging coords (4 x 16B segments for each of A, B)
    int srow[4], sseg[4], swb[4];
    #pragma unroll
    for (int it = 0; it < 4; it++) {
        int idx = tid + (it << 8);          // 0..1023
        srow[it] = idx >> 4;                // 0..63
        sseg[it] = idx & 15;                // 0..15
        swb[it]  = srow[it] * 256 + ((sseg[it] << 4) ^ ((srow[it] & 15) << 4));
    }
    // A spatial decode per staging row
    int abase[4]; // (bimg<<10)+(y0<<5)+x0 without tap shift
    int ay[4], ax[4];
    #pragma unroll
    for (int it = 0; it < 4; it++) {
        int m = bm + srow[it];
        int bimg = m >> 10, s = m & 1023;
        ay[it] = s >> 5; ax[it] = s & 31;
        abase[it] = bimg << 10;
    }

    f32x4 acc[2][2];
    #pragma unroll
    for (int i = 0; i < 2; i++)
        #pragma unroll
        for (int j = 0; j < 2; j++)
            #pragma unroll
            for (int r = 0; r < 4; r++) acc[i][j][r] = 0.f;

    // prologue: stage iter 0 into buffer 0 (tap 0: dy=-1, dx=-1, i0=0)
    #pragma unroll
    for (int it = 0; it < 4; it++) {
        int y = ay[it] - 1, xx = ax[it] - 1;
        float4 av = make_float4(0.f,0.f,0.f,0.f);
        if ((unsigned)y < 32u && (unsigned)xx < 32u)
            av = *(const float4*)(Xd + ((size_t)(abase[it] + (y<<5) + xx) << 8) + (sseg[it] << 3));
        *(float4*)((char*)As[0] + swb[it]) = av;
        float4 bv = *(const float4*)(Wt + (size_t)(bn + srow[it]) * 2304 + (sseg[it] << 3));
        *(float4*)((char*)Bs[0] + swb[it]) = bv;
    }
    __syncthreads();

    int cur = 0;
    for (int t = 0; t < 18; t++) {
        // issue next-tile global loads into registers (hidden under MFMA below)
        float4 ra[4], rb[4];
        const bool has_next = (t + 1 < 18);
        if (has_next) {
            int tn = t + 1;
            int tap = tn >> 1;
            int dy = tap / 3 - 1;
            int dx = tap - (tap / 3) * 3 - 1;
            int i0 = (tn & 1) << 7;
            #pragma unroll
            for (int it = 0; it < 4; it++) {
                int y = ay[it] + dy, xx = ax[it] + dx;
                ra[it] = make_float4(0.f,0.f,0.f,0.f);
                if ((unsigned)y < 32u && (unsigned)xx < 32u)
                    ra[it] = *(const float4*)(Xd + ((size_t)(abase[it] + (y<<5) + xx) << 8) + i0 + (sseg[it] << 3));
                rb[it] = *(const float4*)(Wt + (size_t)(bn + srow[it]) * 2304 + tn * 128 + (sseg[it] << 3));
            }
        }
        // compute on current buffer: 4 k-slices x 4 MFMA
        #pragma unroll
        for (int ks = 0; ks < 4; ks++) {
            bf16x8 af[2], bfr[2];
            #pragma unroll
            for (int i = 0; i < 2; i++)
                af[i] = lds_frag256(As[cur], (wr<<5) + (i<<4) + l16, (ks<<6) + (g<<4));
            #pragma unroll
            for (int j = 0; j < 2; j++)
                bfr[j] = lds_frag256(Bs[cur], (wc<<5) + (j<<4) + l16, (ks<<6) + (g<<4));
            #pragma unroll
            for (int i = 0; i < 2; i++)
                #pragma unroll
                for (int j = 0; j < 2; j++)
                    acc[i][j] = __builtin_amdgcn_mfma_f32_16x16x32_bf16(af[i], bfr[j], acc[i][j], 0, 0, 0);
        }
        // write staged registers to the other buffer
        if (has_next) {
            #pragma unroll
            for (int it = 0; it < 4; it++) {
                *(float4*)((char*)As[cur^1] + swb[it]) = ra[it];
                *(float4*)((char*)Bs[cur^1] + swb[it]) = rb[it];
            }
        }
        __syncthreads();
        cur ^= 1;
    }

    const float bn_s = 0.99999500003749968f;
    #pragma unroll
    for (int i = 0; i < 2; i++) {
        int m = bm + (wr<<5) + (i<<4) + (g<<2);
        #pragma unroll
        for (int j = 0; j < 2; j++) {
            int c = bn + (wc<<5) + (j<<4) + l16;
            float sc = bn_g[c] * bn_s, bb = bn_b[c], bi = bias[c];
            #pragma unroll
            for (int r = 0; r < 4; r++)
                C[(size_t)(m + r) * 256 + c] = fmaxf((acc[i][j][r] + bi) * sc + bb, 0.f);
        }
    }
}

// ================= small prep kernels =================
__global__ void wtrans(const float* __restrict__ in, __hip_bfloat16* __restrict__ o,
                       int K, int N)
{
    int idx = blockIdx.x * 256 + threadIdx.x;
    if (idx >= K * N) return;
    int n = idx / K, k = idx - n * K;
    o[idx] = __float2bfloat16(in[(size_t)k * N + n]);
}

__global__ void wt_kernel(const float* __restrict__ Wf, __hip_bfloat16* __restrict__ Wt)
{
    int o = blockIdx.x;
    int i = threadIdx.x;
    const float* src = Wf + (size_t)(o * 256 + i) * 9;
    __hip_bfloat16* dst = Wt + (size_t)o * 2304 + i;
    #pragma unroll
    for (int tap = 0; tap < 9; tap++)
        dst[tap * 256] = __float2bfloat16(src[tap]);
}

__global__ void cvt_bf16(const float* __restrict__ in, __hip_bfloat16* __restrict__ o)
{
    int i = blockIdx.x * 256 + threadIdx.x;
    float4 v = ((const float4*)in)[i];
    ushort4 h;
    h.x = f2bf(v.x); h.y = f2bf(v.y); h.z = f2bf(v.z); h.w = f2bf(v.w);
    *(ushort4*)(o + (size_t)i * 4) = h;
}

// ================= window attention (bf16 in/out) =================
__launch_bounds__(256)
__global__ void win_attn(const __hip_bfloat16* __restrict__ qkv,
                         __hip_bfloat16* __restrict__ sa_o)
{
    int gw = blockIdx.x * 4 + (threadIdx.x >> 6);
    int lane = threadIdx.x & 63;
    int b  = gw >> 12;
    int g  = (gw >> 2) & 1023;
    int sh = gw & 3;
    int hg = g >> 5, wg = g & 31;
    float q[4], k[4], v[4];
    int rows[4];
    #pragma unroll
    for (int l = 0; l < 4; l++) {
        int h = (hg << 1) + (l >> 1), w = (wg << 1) + (l & 1);
        int row = (b << 12) + (h << 6) + w;
        rows[l] = row;
        const __hip_bfloat16* p = qkv + (size_t)row * 768 + sh * 64 + lane;
        q[l] = __bfloat162float(p[0]);
        k[l] = __bfloat162float(p[256]);
        v[l] = __bfloat162float(p[512]);
    }
    float s[4][4];
    #pragma unroll
    for (int l = 0; l < 4; l++)
        #pragma unroll
        for (int m = 0; m < 4; m++) s[l][m] = q[l] * k[m];
    #pragma unroll
    for (int off = 32; off > 0; off >>= 1)
        #pragma unroll
        for (int l = 0; l < 4; l++)
            #pragma unroll
            for (int m = 0; m < 4; m++)
                s[l][m] += __shfl_xor(s[l][m], off, 64);
    #pragma unroll
    for (int l = 0; l < 4; l++) {
        float s0 = s[l][0]*WSCALE, s1 = s[l][1]*WSCALE, s2 = s[l][2]*WSCALE, s3 = s[l][3]*WSCALE;
        float mx = fmaxf(fmaxf(s0,s1), fmaxf(s2,s3));
        float p0 = __expf(s0-mx), p1 = __expf(s1-mx), p2 = __expf(s2-mx), p3 = __expf(s3-mx);
        float inv = 1.f / (p0+p1+p2+p3);
        float o = (p0*v[0] + p1*v[1] + p2*v[2] + p3*v[3]) * inv;
        sa_o[(size_t)rows[l] * 256 + sh * 64 + lane] = __float2bfloat16(o);
    }
}

// ================= Haar DWT (fp32 in -> bf16 channel-last) =================
__global__ void dwt_kernel(const float* __restrict__ r, __hip_bfloat16* __restrict__ xd)
{
    int t = blockIdx.x * 256 + threadIdx.x;
    int o = t & 63;
    int x = (t >> 6) & 31;
    int y = (t >> 11) & 31;
    int b = t >> 16;
    const float* rb = r + (b << 18);
    int base = ((y << 1) << 6) + (x << 1);
    float a  = rb[(base     ) * 64 + o];
    float bb = rb[(base +  1) * 64 + o];
    float c  = rb[(base + 64) * 64 + o];
    float d  = rb[(base + 65) * 64 + o];
    float ll = 0.5f*(a+bb+c+d), lh = 0.5f*(a+bb-c-d);
    float hl = 0.5f*(a-bb+c-d), hh = 0.5f*(a-bb-c+d);
    __hip_bfloat16* outp = xd + (((b << 10) + (y << 5) + x) << 8) + o;
    outp[0]   = __float2bfloat16(ll);
    outp[64]  = __float2bfloat16(lh);
    outp[128] = __float2bfloat16(hl);
    outp[192] = __float2bfloat16(hh);
}

// ================= Haar IDWT (fp32 in -> bf16 out) =================
__global__ void idwt_kernel(const float* __restrict__ xd, __hip_bfloat16* __restrict__ xi)
{
    int t = blockIdx.x * 256 + threadIdx.x;
    int o = t & 63;
    int x = (t >> 6) & 31;
    int y = (t >> 11) & 31;
    int b = t >> 16;
    const float* p = xd + (((b << 10) + (y << 5) + x) << 8);
    float ll = p[o], lh = p[64+o], hl = p[128+o], hh = p[192+o];
    float y00 = 0.5f*(ll+lh+hl+hh);
    float y01 = 0.5f*(ll+lh-hl-hh);
    float y10 = 0.5f*(ll-lh+hl-hh);
    float y11 = 0.5f*(ll-lh-hl+hh);
    __hip_bfloat16* ob = xi + ((size_t)b << 18);
    int base = ((y << 1) << 6) + (x << 1);
    ob[(size_t)(base     ) * 64 + o] = __float2bfloat16(y00);
    ob[(size_t)(base +  1) * 64 + o] = __float2bfloat16(y01);
    ob[(size_t)(base + 64) * 64 + o] = __float2bfloat16(y10);
    ob[(size_t)(base + 65) * 64 + o] = __float2bfloat16(y11);
}

// ================= LayerNorm over 256 (fp32 in -> bf16 out) =================
__launch_bounds__(256)
__global__ void ln_kernel(const float* __restrict__ X, const float* __restrict__ g,
                          const float* __restrict__ bta, __hip_bfloat16* __restrict__ Y)
{
    int row = blockIdx.x;
    int t = threadIdx.x;
    float x = X[(size_t)row * 256 + t];
    __shared__ float red[4];
    int wv = t >> 6, ln = t & 63;
    float s = x;
    #pragma unroll
    for (int off = 32; off > 0; off >>= 1) s += __shfl_xor(s, off, 64);
    if (ln == 0) red[wv] = s;
    __syncthreads();
    float m = (red[0]+red[1]+red[2]+red[3]) * (1.f/256.f);
    float d = x - m;
    float s2 = d * d;
    #pragma unroll
    for (int off = 32; off > 0; off >>= 1) s2 += __shfl_xor(s2, off, 64);
    __syncthreads();
    if (ln == 0) red[wv] = s2;
    __syncthreads();
    float var = (red[0]+red[1]+red[2]+red[3]) * (1.f/256.f);
    float inv = 1.f / sqrtf(var + WEPS);
    Y[(size_t)row * 256 + t] = __float2bfloat16(d * inv * g[t] + bta[t]);
}

// ================= MFMA flash attention (bf16 out) =================
__launch_bounds__(256)
__global__ void flash_mfma(const __hip_bfloat16* __restrict__ qb,
                           const __hip_bfloat16* __restrict__ kb,
                           const __hip_bfloat16* __restrict__ vt,
                           __hip_bfloat16* __restrict__ ow)
{
    __shared__ unsigned short Ks[4096];
    __shared__ unsigned short Vs[4096];
    const int tid = threadIdx.x;
    const int wv = tid >> 6;
    const int lane = tid & 63;
    const int g = lane >> 4, q16 = lane & 15;
    const int bh = blockIdx.y;
    const int b = bh >> 2, wh = bh & 3;
    const int qbase = (blockIdx.x << 6) + (wv << 4);

    const __hip_bfloat16* qp = qb + ((size_t)((b << 12) + qbase + q16)) * 256 + wh * 64 + g * 8;
    bf16x8 qf0 = *(const bf16x8*)qp;
    bf16x8 qf1 = *(const bf16x8*)(qp + 32);

    const __hip_bfloat16* kbase = kb + ((size_t)bh << 16);
    const __hip_bfloat16* vbase = vt + ((size_t)bh << 16);

    f32x4 oacc[4];
    #pragma unroll
    for (int dc = 0; dc < 4; dc++)
        #pragma unroll
        for (int r = 0; r < 4; r++) oacc[dc][r] = 0.f;
    float m_old = -1e30f, lsum = 0.f;

    for (int t0 = 0; t0 < 1024; t0 += 64) {
        __syncthreads();
        #pragma unroll
        for (int it = 0; it < 2; it++) {
            int off = (tid << 4) + (it << 12);
            int row = off >> 7;
            int inner = off & 127;
            int wb = row * 128 + (inner ^ ((row & 7) << 4));
            float4 kd = *(const float4*)(kbase + (t0 + row) * 64 + (inner >> 1));
            float4 vd = *(const float4*)(vbase + row * 1024 + t0 + (inner >> 1));
            *(float4*)((char*)Ks + wb) = kd;
            *(float4*)((char*)Vs + wb) = vd;
        }
        __syncthreads();

        f32x4 st[4];
        #pragma unroll
        for (int sub = 0; sub < 4; sub++) {
            #pragma unroll
            for (int r = 0; r < 4; r++) st[sub][r] = 0.f;
            bf16x8 k0 = lds_frag(Ks, sub * 16 + q16, g * 16);
            bf16x8 k1 = lds_frag(Ks, sub * 16 + q16, 64 + g * 16);
            st[sub] = __builtin_amdgcn_mfma_f32_16x16x32_bf16(k0, qf0, st[sub], 0, 0, 0);
            st[sub] = __builtin_amdgcn_mfma_f32_16x16x32_bf16(k1, qf1, st[sub], 0, 0, 0);
        }

        float mx = -1e30f;
        float s[4][4];
        #pragma unroll
        for (int t = 0; t < 4; t++)
            #pragma unroll
            for (int r = 0; r < 4; r++) {
                float v = st[t][r] * WSCALE;
                s[t][r] = v;
                mx = fmaxf(mx, v);
            }
        mx = fmaxf(mx, __shfl_xor(mx, 16, 64));
        mx = fmaxf(mx, __shfl_xor(mx, 32, 64));
        float m_new = fmaxf(m_old, mx);
        float alpha = __expf(m_old - m_new);
        float psum = 0.f;
        unsigned pk[4][2];
        #pragma unroll
        for (int t = 0; t < 4; t++) {
            float p0 = __expf(s[t][0] - m_new), p1 = __expf(s[t][1] - m_new);
            float p2 = __expf(s[t][2] - m_new), p3 = __expf(s[t][3] - m_new);
            psum += (p0 + p1) + (p2 + p3);
            pk[t][0] = pack2bf(p0, p1);
            pk[t][1] = pack2bf(p2, p3);
        }
        psum += __shfl_xor(psum, 16, 64);
        psum += __shfl_xor(psum, 32, 64);
        lsum = lsum * alpha + psum;
        m_old = m_new;

        #pragma unroll
        for (int r = 0; r < 4; r++) {
            float sc = __shfl(alpha, (g << 2) + r, 64);
            #pragma unroll
            for (int dc = 0; dc < 4; dc++) oacc[dc][r] *= sc;
        }

        bool ghi = (g & 2) != 0;
        unsigned pkA0[2], pkA1[2];
        pkA0[0] = ghi ? pk[1][0] : pk[0][0];
        pkA0[1] = ghi ? pk[1][1] : pk[0][1];
        pkA1[0] = ghi ? pk[3][0] : pk[2][0];
        pkA1[1] = ghi ? pk[3][1] : pk[2][1];
        union { int u[4]; bf16x8 v; } A0, A1;
        #pragma unroll
        for (int c = 0; c < 4; c++) {
            int src = (((2 * g + (c >> 1)) & 3) << 4) | q16;
            A0.u[c] = __shfl((int)pkA0[c & 1], src, 64);
            A1.u[c] = __shfl((int)pkA1[c & 1], src, 64);
        }

        #pragma unroll
        for (int dc = 0; dc < 4; dc++) {
            bf16x8 v0 = lds_frag(Vs, dc * 16 + q16, g * 16);
            bf16x8 v1 = lds_frag(Vs, dc * 16 + q16, 64 + g * 16);
            oacc[dc] = __builtin_amdgcn_mfma_f32_16x16x32_bf16(A0.v, v0, oacc[dc], 0, 0, 0);
            oacc[dc] = __builtin_amdgcn_mfma_f32_16x16x32_bf16(A1.v, v1, oacc[dc], 0, 0, 0);
        }
    }

    #pragma unroll
    for (int r = 0; r < 4; r++) {
        float inv = 1.f / __shfl(lsum, (g << 2) + r, 64);
        int qrow = (b << 12) + qbase + (g << 2) + r;
        #pragma unroll
        for (int dc = 0; dc < 4; dc++)
            ow[(size_t)qrow * 256 + wh * 64 + dc * 16 + q16] =
                __float2bfloat16(oacc[dc][r] * inv);
    }
}

extern "C" void kernel_launch(void* const* d_in, const int* in_sizes, int n_in,
                              void* d_out, int out_size, void* d_ws, size_t ws_size,
                              hipStream_t stream)
{
    const float* x        = (const float*)d_in[0];
    const float* wq_w     = (const float*)d_in[1];
    const float* kv_ln_g  = (const float*)d_in[2];
    const float* kv_ln_b  = (const float*)d_in[3];
    const float* wkv_w    = (const float*)d_in[4];
    const float* wkv_b    = (const float*)d_in[5];
    const float* wproj_w  = (const float*)d_in[6];
    const float* wproj_b  = (const float*)d_in[7];
    const float* reduce_w = (const float*)d_in[8];
    const float* reduce_b = (const float*)d_in[9];
    const float* rbn_g    = (const float*)d_in[10];
    const float* rbn_b    = (const float*)d_in[11];
    const float* filter_w = (const float*)d_in[12];
    const float* filter_b = (const float*)d_in[13];
    const float* fbn_g    = (const float*)d_in[14];
    const float* fbn_b    = (const float*)d_in[15];
    const float* sqkv_w   = (const float*)d_in[16];
    const float* sproj_w  = (const float*)d_in[17];
    const float* sproj_b  = (const float*)d_in[18];
    float* out = (float*)d_out;
    float* ws  = (float*)d_ws;

    // workspace layout (float units)
    __hip_bfloat16* qkvb  = (__hip_bfloat16*)(ws);             // 12,582,912 bf16
    __hip_bfloat16* owb   = (__hip_bfloat16*)(ws);             // reuse after win_attn
    __hip_bfloat16* sa_ob = (__hip_bfloat16*)(ws + 6291456);   // 4,194,304 bf16
    __hip_bfloat16* xb    = (__hip_bfloat16*)(ws + 8388608);   // 8,388,608 bf16
    __hip_bfloat16* sqkvT = (__hip_bfloat16*)(ws + 12582912);  // 393,216 bf16
    __hip_bfloat16* wqT   = (__hip_bfloat16*)(ws + 12779520);  // 131,072 bf16
    __hip_bfloat16* redT  = (__hip_bfloat16*)(ws + 12845056);  // 32,768 bf16
    __hip_bfloat16* sprojT= (__hip_bfloat16*)(ws + 12861440);  // 65,536 bf16
    __hip_bfloat16* wkvT  = (__hip_bfloat16*)(ws + 12894208);  // 131,072 bf16
    __hip_bfloat16* wprojT= (__hip_bfloat16*)(ws + 13025280);  // 81,920 bf16
    __hip_bfloat16* wt2b  = (__hip_bfloat16*)(ws + 13066240);  // 589,824 bf16
    float* rbuf  = ws + 13361152;                              // 1,048,576 f
    __hip_bfloat16* xd1b  = (__hip_bfloat16*)(ws + 14409728);  // 1,048,576 bf16
    float* xd2   = ws + 14934016;                              // 1,048,576 f
    __hip_bfloat16* kvinb = (__hip_bfloat16*)(ws + 15982592);  // 1,048,576 bf16
    __hip_bfloat16* xidwtb= (__hip_bfloat16*)(ws + 16506880);  // 1,048,576 bf16
    __hip_bfloat16* qbw   = (__hip_bfloat16*)(ws + 17031168);  // 4,194,304 bf16
    __hip_bfloat16* kbb   = (__hip_bfloat16*)(ws + 19128320);  // 1,048,576 bf16
    __hip_bfloat16* vtb   = (__hip_bfloat16*)(ws + 19652608);  // 1,048,576 bf16

    dim3 blk(256);

    // prep: x -> bf16, weight transposes
    cvt_bf16<<<dim3(8192), blk, 0, stream>>>(x, xb);
    wtrans<<<dim3(1536), blk, 0, stream>>>(sqkv_w, sqkvT, 512, 768);
    wtrans<<<dim3(512),  blk, 0, stream>>>(wq_w, wqT, 512, 256);
    wtrans<<<dim3(128),  blk, 0, stream>>>(reduce_w, redT, 512, 64);
    wtrans<<<dim3(256),  blk, 0, stream>>>(sproj_w, sprojT, 256, 256);
    wtrans<<<dim3(512),  blk, 0, stream>>>(wkv_w, wkvT, 256, 512);
    wtrans<<<dim3(320),  blk, 0, stream>>>(wproj_w, wprojT, 320, 256);
    wt_kernel<<<dim3(256), blk, 0, stream>>>(filter_w, wt2b);

    // 1. qkv = xb @ sqkv_w  (bf16 out)
    gemm_bf16<EPI_NONE,1><<<dim3(6,128), blk, 0, stream>>>(xb, 512, sqkvT, 512, qkvb, 768,
                                                           768, nullptr, nullptr, nullptr);
    // 2. window attention (bf16 -> bf16)
    win_attn<<<dim3(4096), blk, 0, stream>>>(qkvb, sa_ob);
    // 3. sa_out -> out cols [0,256)
    gemm_bf16<EPI_BIAS,0><<<dim3(2,128), blk, 0, stream>>>(sa_ob, 256, sprojT, 256, out, 512,
                                                           256, sproj_b, nullptr, nullptr);
    // 4. qw = xb @ wq_w (bf16 out)
    gemm_bf16<EPI_NONE,1><<<dim3(2,128), blk, 0, stream>>>(xb, 512, wqT, 512, qbw, 256,
                                                           256, nullptr, nullptr, nullptr);
    // 5. r = relu(bn(xb @ reduce_w + b))  (fp32 out, N=64)
    gemm_bf16<EPI_BN_RELU,0><<<dim3(1,128), blk, 0, stream>>>(xb, 512, redT, 512, rbuf, 64,
                                                              64, reduce_b, rbn_g, rbn_b);
    // 6. DWT -> bf16
    dwt_kernel<<<dim3(1024), blk, 0, stream>>>(rbuf, xd1b);
    // 7. 3x3 conv MFMA + BN + ReLU -> fp32 xd2  (64x64 tiles, 256 blocks, dbuf)
    conv3_mfma<<<dim3(4,64), blk, 0, stream>>>(xd1b, wt2b, xd2, filter_b, fbn_g, fbn_b);
    // 8. layernorm -> bf16
    ln_kernel<<<dim3(4096), blk, 0, stream>>>(xd2, kv_ln_g, kv_ln_b, kvinb);
    // 9. kv GEMM -> bf16 K + transposed V
    gemm_kv_mfma<<<dim3(4,32), blk, 0, stream>>>(kvinb, wkvT, kbb, vtb, wkv_b);
    // 10. IDWT -> bf16
    idwt_kernel<<<dim3(1024), blk, 0, stream>>>(xd2, xidwtb);
    // 11. flash attention -> bf16 ow (reuses qkvb space)
    flash_mfma<<<dim3(64,16), blk, 0, stream>>>(qbw, kbb, vtb, owb);
    // 12. fused wproj: [ow | x_idwt] @ wproj + b -> out cols [256,512)
    gemm_wproj<<<dim3(2,128), blk, 0, stream>>>(owb, xidwtb, wprojT, out + 256, wproj_b);
}

// Round 6
// 209.849 us; speedup vs baseline: 7.7787x; 1.0335x over previous
//
#include <hip/hip_runtime.h>
#include <hip/hip_bf16.h>
#include <math.h>

#define WEPS 1e-5f
#define WSCALE 0.125f

enum { EPI_NONE=0, EPI_BIAS=1, EPI_BN_RELU=2 };

typedef __attribute__((ext_vector_type(8))) short bf16x8;
typedef __attribute__((ext_vector_type(4))) float f32x4;

static __device__ inline unsigned short f2bf(float f) {
    __hip_bfloat16 h = __float2bfloat16(f);
    return *(unsigned short*)&h;
}
static __device__ inline unsigned pack2bf(float a, float b) {
    return (unsigned)f2bf(a) | ((unsigned)f2bf(b) << 16);
}

// swizzled LDS 16B fragment read: 128B rows, byte ^= (row&7)<<4
static __device__ inline bf16x8 lds_frag(const unsigned short* base, int row, int inner) {
    int byte = row * 128 + (inner ^ ((row & 7) << 4));
    return *(const bf16x8*)((const char*)base + byte);
}
// swizzled LDS 16B fragment read: 256B rows, byte ^= (row&15)<<4
static __device__ inline bf16x8 lds_frag256(const unsigned short* base, int row, int inner) {
    int byte = row * 256 + (inner ^ ((row & 15) << 4));
    return *(const bf16x8*)((const char*)base + byte);
}

// ================= bf16 MFMA GEMM template =================
// C[M,N] = oscale * A[M,K](bf16) @ Bt[N,K]^T (+epilogue). 128x128 tile, BK=64.
template<int EPI, int OBF16>
__launch_bounds__(256)
__global__ void gemm_bf16(const __hip_bfloat16* __restrict__ A, int lda,
                          const __hip_bfloat16* __restrict__ Bt, int K,
                          void* __restrict__ Cv, int ldc, int N,
                          const float* __restrict__ bias,
                          const float* __restrict__ bn_g,
                          const float* __restrict__ bn_b,
                          float oscale)
{
    __shared__ unsigned short As[8192];
    __shared__ unsigned short Bs[8192];
    const int tid = threadIdx.x;
    const int lane = tid & 63, wv = tid >> 6;
    const int g = lane >> 4, l16 = lane & 15;
    const int wr = wv >> 1, wc = wv & 1;
    const int bm = blockIdx.y << 7;
    const int bn = blockIdx.x << 7;
    f32x4 acc[4][4];
    #pragma unroll
    for (int i = 0; i < 4; i++)
        #pragma unroll
        for (int j = 0; j < 4; j++)
            #pragma unroll
            for (int r = 0; r < 4; r++) acc[i][j][r] = 0.f;

    for (int k0 = 0; k0 < K; k0 += 64) {
        __syncthreads();
        #pragma unroll
        for (int it = 0; it < 4; it++) {
            int idx = tid + (it << 8);
            int row = idx >> 3, seg = idx & 7;
            int wb = row * 128 + ((seg << 4) ^ ((row & 7) << 4));
            float4 av = *(const float4*)(A + (size_t)(bm + row) * lda + k0 + (seg << 3));
            *(float4*)((char*)As + wb) = av;
            int col = bn + row;
            float4 bv = make_float4(0.f,0.f,0.f,0.f);
            if (col < N) bv = *(const float4*)(Bt + (size_t)col * K + k0 + (seg << 3));
            *(float4*)((char*)Bs + wb) = bv;
        }
        __syncthreads();
        #pragma unroll
        for (int ks = 0; ks < 2; ks++) {
            bf16x8 af[4], bfr[4];
            #pragma unroll
            for (int i = 0; i < 4; i++)
                af[i] = lds_frag(As, (wr<<6) + (i<<4) + l16, (ks<<6) + (g<<4));
            #pragma unroll
            for (int j = 0; j < 4; j++)
                bfr[j] = lds_frag(Bs, (wc<<6) + (j<<4) + l16, (ks<<6) + (g<<4));
            #pragma unroll
            for (int i = 0; i < 4; i++)
                #pragma unroll
                for (int j = 0; j < 4; j++)
                    acc[i][j] = __builtin_amdgcn_mfma_f32_16x16x32_bf16(af[i], bfr[j], acc[i][j], 0, 0, 0);
        }
    }
    const float bn_s = 0.99999500003749968f;
    #pragma unroll
    for (int i = 0; i < 4; i++) {
        int m = bm + (wr<<6) + (i<<4) + (g<<2);
        #pragma unroll
        for (int j = 0; j < 4; j++) {
            int c = bn + (wc<<6) + (j<<4) + l16;
            if (c >= N) continue;
            float bi = (EPI != EPI_NONE) ? bias[c] : 0.f;
            float sc = 1.f, bb = 0.f;
            if (EPI == EPI_BN_RELU) { sc = bn_g[c] * bn_s; bb = bn_b[c]; }
            #pragma unroll
            for (int r = 0; r < 4; r++) {
                float t = acc[i][j][r] * oscale + bi;
                if (EPI == EPI_BN_RELU) t = fmaxf(t * sc + bb, 0.f);
                if (OBF16) ((__hip_bfloat16*)Cv)[(size_t)(m+r)*ldc + c] = __float2bfloat16(t);
                else       ((float*)Cv)[(size_t)(m+r)*ldc + c] = t;
            }
        }
    }
}

// ================= kv GEMM (bf16 MFMA): K row-major + V transposed out =================
__launch_bounds__(256)
__global__ void gemm_kv_mfma(const __hip_bfloat16* __restrict__ A,
                             const __hip_bfloat16* __restrict__ Bt,
                             __hip_bfloat16* __restrict__ kbo,   // [16][1024][64]
                             __hip_bfloat16* __restrict__ vto,   // [16][64][1024]
                             const float* __restrict__ bias)
{
    __shared__ unsigned short As[8192];
    __shared__ unsigned short Bs[8192];
    const int tid = threadIdx.x;
    const int lane = tid & 63, wv = tid >> 6;
    const int g = lane >> 4, l16 = lane & 15;
    const int wr = wv >> 1, wc = wv & 1;
    const int bm = blockIdx.y << 7;
    const int bn = blockIdx.x << 7;
    f32x4 acc[4][4];
    #pragma unroll
    for (int i = 0; i < 4; i++)
        #pragma unroll
        for (int j = 0; j < 4; j++)
            #pragma unroll
            for (int r = 0; r < 4; r++) acc[i][j][r] = 0.f;

    for (int k0 = 0; k0 < 256; k0 += 64) {
        __syncthreads();
        #pragma unroll
        for (int it = 0; it < 4; it++) {
            int idx = tid + (it << 8);
            int row = idx >> 3, seg = idx & 7;
            int wb = row * 128 + ((seg << 4) ^ ((row & 7) << 4));
            float4 av = *(const float4*)(A + (size_t)(bm + row) * 256 + k0 + (seg << 3));
            *(float4*)((char*)As + wb) = av;
            float4 bv = *(const float4*)(Bt + (size_t)(bn + row) * 256 + k0 + (seg << 3));
            *(float4*)((char*)Bs + wb) = bv;
        }
        __syncthreads();
        #pragma unroll
        for (int ks = 0; ks < 2; ks++) {
            bf16x8 af[4], bfr[4];
            #pragma unroll
            for (int i = 0; i < 4; i++)
                af[i] = lds_frag(As, (wr<<6) + (i<<4) + l16, (ks<<6) + (g<<4));
            #pragma unroll
            for (int j = 0; j < 4; j++)
                bfr[j] = lds_frag(Bs, (wc<<6) + (j<<4) + l16, (ks<<6) + (g<<4));
            #pragma unroll
            for (int i = 0; i < 4; i++)
                #pragma unroll
                for (int j = 0; j < 4; j++)
                    acc[i][j] = __builtin_amdgcn_mfma_f32_16x16x32_bf16(af[i], bfr[j], acc[i][j], 0, 0, 0);
        }
    }
    #pragma unroll
    for (int i = 0; i < 4; i++) {
        int m = bm + (wr<<6) + (i<<4) + (g<<2);
        int bimg = m >> 10, tkn0 = m & 1023;
        #pragma unroll
        for (int j = 0; j < 4; j++) {
            int c = bn + (wc<<6) + (j<<4) + l16;
            if (c < 256) {          // K: [bh][token][d]
                int wh = c >> 6, d0 = c & 63;
                __hip_bfloat16* kp = kbo + (((size_t)((bimg<<2)+wh)) << 16) + (size_t)tkn0*64 + d0;
                #pragma unroll
                for (int r = 0; r < 4; r++)
                    kp[r*64] = __float2bfloat16(acc[i][j][r] + bias[c]);
            } else {                // V: [bh][d][token]
                int c2 = c - 256;
                int wh = c2 >> 6, d = c2 & 63;
                float bi = bias[256 + c2];
                ushort4 h;
                h.x = f2bf(acc[i][j][0] + bi);
                h.y = f2bf(acc[i][j][1] + bi);
                h.z = f2bf(acc[i][j][2] + bi);
                h.w = f2bf(acc[i][j][3] + bi);
                *(ushort4*)(vto + (((size_t)((bimg<<2)+wh)) << 16) + (size_t)d*1024 + tkn0) = h;
            }
        }
    }
}

// ================= fused wproj GEMM: [ow | x_idwt] @ wprojT + b =================
__launch_bounds__(256)
__global__ void gemm_wproj(const __hip_bfloat16* __restrict__ A1,
                           const __hip_bfloat16* __restrict__ A2,
                           const __hip_bfloat16* __restrict__ Bt,  // [256][320]
                           float* __restrict__ C,                  // out+256, ldc=512
                           const float* __restrict__ bias)
{
    __shared__ unsigned short As[8192];
    __shared__ unsigned short Bs[8192];
    const int tid = threadIdx.x;
    const int lane = tid & 63, wv = tid >> 6;
    const int g = lane >> 4, l16 = lane & 15;
    const int wr = wv >> 1, wc = wv & 1;
    const int bm = blockIdx.y << 7;
    const int bn = blockIdx.x << 7;
    f32x4 acc[4][4];
    #pragma unroll
    for (int i = 0; i < 4; i++)
        #pragma unroll
        for (int j = 0; j < 4; j++)
            #pragma unroll
            for (int r = 0; r < 4; r++) acc[i][j][r] = 0.f;

    for (int k0 = 0; k0 < 320; k0 += 64) {
        __syncthreads();
        #pragma unroll
        for (int it = 0; it < 4; it++) {
            int idx = tid + (it << 8);
            int row = idx >> 3, seg = idx & 7;
            int wb = row * 128 + ((seg << 4) ^ ((row & 7) << 4));
            float4 av;
            if (k0 < 256)
                av = *(const float4*)(A1 + (size_t)(bm + row) * 256 + k0 + (seg << 3));
            else
                av = *(const float4*)(A2 + (size_t)(bm + row) * 64 + (k0 - 256) + (seg << 3));
            *(float4*)((char*)As + wb) = av;
            float4 bv = *(const float4*)(Bt + (size_t)(bn + row) * 320 + k0 + (seg << 3));
            *(float4*)((char*)Bs + wb) = bv;
        }
        __syncthreads();
        #pragma unroll
        for (int ks = 0; ks < 2; ks++) {
            bf16x8 af[4], bfr[4];
            #pragma unroll
            for (int i = 0; i < 4; i++)
                af[i] = lds_frag(As, (wr<<6) + (i<<4) + l16, (ks<<6) + (g<<4));
            #pragma unroll
            for (int j = 0; j < 4; j++)
                bfr[j] = lds_frag(Bs, (wc<<6) + (j<<4) + l16, (ks<<6) + (g<<4));
            #pragma unroll
            for (int i = 0; i < 4; i++)
                #pragma unroll
                for (int j = 0; j < 4; j++)
                    acc[i][j] = __builtin_amdgcn_mfma_f32_16x16x32_bf16(af[i], bfr[j], acc[i][j], 0, 0, 0);
        }
    }
    #pragma unroll
    for (int i = 0; i < 4; i++) {
        int m = bm + (wr<<6) + (i<<4) + (g<<2);
        #pragma unroll
        for (int j = 0; j < 4; j++) {
            int c = bn + (wc<<6) + (j<<4) + l16;
            float bi = bias[c];
            #pragma unroll
            for (int r = 0; r < 4; r++)
                C[(size_t)(m+r)*512 + c] = acc[i][j][r] + bi;
        }
    }
}

// ================= 3x3 conv: bf16 MFMA, 64x64 tile, BK=128, double-buffered =====
__launch_bounds__(256)
__global__ void conv3_mfma(const __hip_bfloat16* __restrict__ Xd,
                           const __hip_bfloat16* __restrict__ Wt,
                           float* __restrict__ C,
                           const float* __restrict__ bias,
                           const float* __restrict__ bn_g,
                           const float* __restrict__ bn_b)
{
    __shared__ unsigned short As[2][8192];
    __shared__ unsigned short Bs[2][8192];
    const int tid = threadIdx.x;
    const int lane = tid & 63, wv = tid >> 6;
    const int g = lane >> 4, l16 = lane & 15;
    const int wr = wv >> 1, wc = wv & 1;
    const int bm = blockIdx.y << 6;
    const int bn = blockIdx.x << 6;

    int srow[4], sseg[4], swb[4];
    #pragma unroll
    for (int it = 0; it < 4; it++) {
        int idx = tid + (it << 8);
        srow[it] = idx >> 4;
        sseg[it] = idx & 15;
        swb[it]  = srow[it] * 256 + ((sseg[it] << 4) ^ ((srow[it] & 15) << 4));
    }
    int abase[4], ay[4], ax[4];
    #pragma unroll
    for (int it = 0; it < 4; it++) {
        int m = bm + srow[it];
        int bimg = m >> 10, s = m & 1023;
        ay[it] = s >> 5; ax[it] = s & 31;
        abase[it] = bimg << 10;
    }

    f32x4 acc[2][2];
    #pragma unroll
    for (int i = 0; i < 2; i++)
        #pragma unroll
        for (int j = 0; j < 2; j++)
            #pragma unroll
            for (int r = 0; r < 4; r++) acc[i][j][r] = 0.f;

    #pragma unroll
    for (int it = 0; it < 4; it++) {
        int y = ay[it] - 1, xx = ax[it] - 1;
        float4 av = make_float4(0.f,0.f,0.f,0.f);
        if ((unsigned)y < 32u && (unsigned)xx < 32u)
            av = *(const float4*)(Xd + ((size_t)(abase[it] + (y<<5) + xx) << 8) + (sseg[it] << 3));
        *(float4*)((char*)As[0] + swb[it]) = av;
        float4 bv = *(const float4*)(Wt + (size_t)(bn + srow[it]) * 2304 + (sseg[it] << 3));
        *(float4*)((char*)Bs[0] + swb[it]) = bv;
    }
    __syncthreads();

    int cur = 0;
    for (int t = 0; t < 18; t++) {
        float4 ra[4], rb[4];
        const bool has_next = (t + 1 < 18);
        if (has_next) {
            int tn = t + 1;
            int tap = tn >> 1;
            int dy = tap / 3 - 1;
            int dx = tap - (tap / 3) * 3 - 1;
            int i0 = (tn & 1) << 7;
            #pragma unroll
            for (int it = 0; it < 4; it++) {
                int y = ay[it] + dy, xx = ax[it] + dx;
                ra[it] = make_float4(0.f,0.f,0.f,0.f);
                if ((unsigned)y < 32u && (unsigned)xx < 32u)
                    ra[it] = *(const float4*)(Xd + ((size_t)(abase[it] + (y<<5) + xx) << 8) + i0 + (sseg[it] << 3));
                rb[it] = *(const float4*)(Wt + (size_t)(bn + srow[it]) * 2304 + tn * 128 + (sseg[it] << 3));
            }
        }
        #pragma unroll
        for (int ks = 0; ks < 4; ks++) {
            bf16x8 af[2], bfr[2];
            #pragma unroll
            for (int i = 0; i < 2; i++)
                af[i] = lds_frag256(As[cur], (wr<<5) + (i<<4) + l16, (ks<<6) + (g<<4));
            #pragma unroll
            for (int j = 0; j < 2; j++)
                bfr[j] = lds_frag256(Bs[cur], (wc<<5) + (j<<4) + l16, (ks<<6) + (g<<4));
            #pragma unroll
            for (int i = 0; i < 2; i++)
                #pragma unroll
                for (int j = 0; j < 2; j++)
                    acc[i][j] = __builtin_amdgcn_mfma_f32_16x16x32_bf16(af[i], bfr[j], acc[i][j], 0, 0, 0);
        }
        if (has_next) {
            #pragma unroll
            for (int it = 0; it < 4; it++) {
                *(float4*)((char*)As[cur^1] + swb[it]) = ra[it];
                *(float4*)((char*)Bs[cur^1] + swb[it]) = rb[it];
            }
        }
        __syncthreads();
        cur ^= 1;
    }

    const float bn_s = 0.99999500003749968f;
    #pragma unroll
    for (int i = 0; i < 2; i++) {
        int m = bm + (wr<<5) + (i<<4) + (g<<2);
        #pragma unroll
        for (int j = 0; j < 2; j++) {
            int c = bn + (wc<<5) + (j<<4) + l16;
            float sc = bn_g[c] * bn_s, bb = bn_b[c], bi = bias[c];
            #pragma unroll
            for (int r = 0; r < 4; r++)
                C[(size_t)(m + r) * 256 + c] = fmaxf((acc[i][j][r] + bi) * sc + bb, 0.f);
        }
    }
}

// ================= small prep kernels =================
__global__ void wtrans(const float* __restrict__ in, __hip_bfloat16* __restrict__ o,
                       int K, int N)
{
    int idx = blockIdx.x * 256 + threadIdx.x;
    if (idx >= K * N) return;
    int n = idx / K, k = idx - n * K;
    o[idx] = __float2bfloat16(in[(size_t)k * N + n]);
}

__global__ void wt_kernel(const float* __restrict__ Wf, __hip_bfloat16* __restrict__ Wt)
{
    int o = blockIdx.x;
    int i = threadIdx.x;
    const float* src = Wf + (size_t)(o * 256 + i) * 9;
    __hip_bfloat16* dst = Wt + (size_t)o * 2304 + i;
    #pragma unroll
    for (int tap = 0; tap < 9; tap++)
        dst[tap * 256] = __float2bfloat16(src[tap]);
}

__global__ void cvt_bf16(const float* __restrict__ in, __hip_bfloat16* __restrict__ o)
{
    int i = blockIdx.x * 256 + threadIdx.x;
    float4 v = ((const float4*)in)[i];
    ushort4 h;
    h.x = f2bf(v.x); h.y = f2bf(v.y); h.z = f2bf(v.z); h.w = f2bf(v.w);
    *(ushort4*)(o + (size_t)i * 4) = h;
}

// ================= window attention (bf16 in/out) =================
__launch_bounds__(256)
__global__ void win_attn(const __hip_bfloat16* __restrict__ qkv,
                         __hip_bfloat16* __restrict__ sa_o)
{
    int gw = blockIdx.x * 4 + (threadIdx.x >> 6);
    int lane = threadIdx.x & 63;
    int b  = gw >> 12;
    int g  = (gw >> 2) & 1023;
    int sh = gw & 3;
    int hg = g >> 5, wg = g & 31;
    float q[4], k[4], v[4];
    int rows[4];
    #pragma unroll
    for (int l = 0; l < 4; l++) {
        int h = (hg << 1) + (l >> 1), w = (wg << 1) + (l & 1);
        int row = (b << 12) + (h << 6) + w;
        rows[l] = row;
        const __hip_bfloat16* p = qkv + (size_t)row * 768 + sh * 64 + lane;
        q[l] = __bfloat162float(p[0]);
        k[l] = __bfloat162float(p[256]);
        v[l] = __bfloat162float(p[512]);
    }
    float s[4][4];
    #pragma unroll
    for (int l = 0; l < 4; l++)
        #pragma unroll
        for (int m = 0; m < 4; m++) s[l][m] = q[l] * k[m];
    #pragma unroll
    for (int off = 32; off > 0; off >>= 1)
        #pragma unroll
        for (int l = 0; l < 4; l++)
            #pragma unroll
            for (int m = 0; m < 4; m++)
                s[l][m] += __shfl_xor(s[l][m], off, 64);
    #pragma unroll
    for (int l = 0; l < 4; l++) {
        float s0 = s[l][0]*WSCALE, s1 = s[l][1]*WSCALE, s2 = s[l][2]*WSCALE, s3 = s[l][3]*WSCALE;
        float mx = fmaxf(fmaxf(s0,s1), fmaxf(s2,s3));
        float p0 = __expf(s0-mx), p1 = __expf(s1-mx), p2 = __expf(s2-mx), p3 = __expf(s3-mx);
        float inv = 1.f / (p0+p1+p2+p3);
        float o = (p0*v[0] + p1*v[1] + p2*v[2] + p3*v[3]) * inv;
        sa_o[(size_t)rows[l] * 256 + sh * 64 + lane] = __float2bfloat16(o);
    }
}

// ================= Haar DWT (fp32 in -> bf16 channel-last) =================
__global__ void dwt_kernel(const float* __restrict__ r, __hip_bfloat16* __restrict__ xd)
{
    int t = blockIdx.x * 256 + threadIdx.x;
    int o = t & 63;
    int x = (t >> 6) & 31;
    int y = (t >> 11) & 31;
    int b = t >> 16;
    const float* rb = r + (b << 18);
    int base = ((y << 1) << 6) + (x << 1);
    float a  = rb[(base     ) * 64 + o];
    float bb = rb[(base +  1) * 64 + o];
    float c  = rb[(base + 64) * 64 + o];
    float d  = rb[(base + 65) * 64 + o];
    float ll = 0.5f*(a+bb+c+d), lh = 0.5f*(a+bb-c-d);
    float hl = 0.5f*(a-bb+c-d), hh = 0.5f*(a-bb-c+d);
    __hip_bfloat16* outp = xd + (((b << 10) + (y << 5) + x) << 8) + o;
    outp[0]   = __float2bfloat16(ll);
    outp[64]  = __float2bfloat16(lh);
    outp[128] = __float2bfloat16(hl);
    outp[192] = __float2bfloat16(hh);
}

// ================= Haar IDWT (fp32 in -> bf16 out) =================
__global__ void idwt_kernel(const float* __restrict__ xd, __hip_bfloat16* __restrict__ xi)
{
    int t = blockIdx.x * 256 + threadIdx.x;
    int o = t & 63;
    int x = (t >> 6) & 31;
    int y = (t >> 11) & 31;
    int b = t >> 16;
    const float* p = xd + (((b << 10) + (y << 5) + x) << 8);
    float ll = p[o], lh = p[64+o], hl = p[128+o], hh = p[192+o];
    float y00 = 0.5f*(ll+lh+hl+hh);
    float y01 = 0.5f*(ll+lh-hl-hh);
    float y10 = 0.5f*(ll-lh+hl-hh);
    float y11 = 0.5f*(ll-lh-hl+hh);
    __hip_bfloat16* ob = xi + ((size_t)b << 18);
    int base = ((y << 1) << 6) + (x << 1);
    ob[(size_t)(base     ) * 64 + o] = __float2bfloat16(y00);
    ob[(size_t)(base +  1) * 64 + o] = __float2bfloat16(y01);
    ob[(size_t)(base + 64) * 64 + o] = __float2bfloat16(y10);
    ob[(size_t)(base + 65) * 64 + o] = __float2bfloat16(y11);
}

// ================= LayerNorm over 256 (fp32 in -> bf16 out) =================
__launch_bounds__(256)
__global__ void ln_kernel(const float* __restrict__ X, const float* __restrict__ g,
                          const float* __restrict__ bta, __hip_bfloat16* __restrict__ Y)
{
    int row = blockIdx.x;
    int t = threadIdx.x;
    float x = X[(size_t)row * 256 + t];
    __shared__ float red[4];
    int wv = t >> 6, ln = t & 63;
    float s = x;
    #pragma unroll
    for (int off = 32; off > 0; off >>= 1) s += __shfl_xor(s, off, 64);
    if (ln == 0) red[wv] = s;
    __syncthreads();
    float m = (red[0]+red[1]+red[2]+red[3]) * (1.f/256.f);
    float d = x - m;
    float s2 = d * d;
    #pragma unroll
    for (int off = 32; off > 0; off >>= 1) s2 += __shfl_xor(s2, off, 64);
    __syncthreads();
    if (ln == 0) red[wv] = s2;
    __syncthreads();
    float var = (red[0]+red[1]+red[2]+red[3]) * (1.f/256.f);
    float inv = 1.f / sqrtf(var + WEPS);
    Y[(size_t)row * 256 + t] = __float2bfloat16(d * inv * g[t] + bta[t]);
}

// ================= MFMA flash attention (defer-max, lane-local lsum) =================
// qb holds PRE-SCALED q (x 0.125). Scores = raw MFMA output.
__launch_bounds__(256)
__global__ void flash_mfma(const __hip_bfloat16* __restrict__ qb,
                           const __hip_bfloat16* __restrict__ kb,
                           const __hip_bfloat16* __restrict__ vt,
                           __hip_bfloat16* __restrict__ ow)
{
    __shared__ unsigned short Ks[4096];
    __shared__ unsigned short Vs[4096];
    const int tid = threadIdx.x;
    const int wv = tid >> 6;
    const int lane = tid & 63;
    const int g = lane >> 4, q16 = lane & 15;
    const int bh = blockIdx.y;
    const int b = bh >> 2, wh = bh & 3;
    const int qbase = (blockIdx.x << 6) + (wv << 4);

    const __hip_bfloat16* qp = qb + ((size_t)((b << 12) + qbase + q16)) * 256 + wh * 64 + g * 8;
    bf16x8 qf0 = *(const bf16x8*)qp;
    bf16x8 qf1 = *(const bf16x8*)(qp + 32);

    const __hip_bfloat16* kbase = kb + ((size_t)bh << 16);
    const __hip_bfloat16* vbase = vt + ((size_t)bh << 16);

    f32x4 oacc[4];
    #pragma unroll
    for (int dc = 0; dc < 4; dc++)
        #pragma unroll
        for (int r = 0; r < 4; r++) oacc[dc][r] = 0.f;
    float m_cur = -1e30f;       // running max for q = q16 (consistent across g)
    float lsum_part = 0.f;      // lane-local partial sum for q = q16

    for (int t0 = 0; t0 < 1024; t0 += 64) {
        __syncthreads();
        #pragma unroll
        for (int it = 0; it < 2; it++) {
            int off = (tid << 4) + (it << 12);
            int row = off >> 7;
            int inner = off & 127;
            int wb = row * 128 + (inner ^ ((row & 7) << 4));
            float4 kd = *(const float4*)(kbase + (t0 + row) * 64 + (inner >> 1));
            float4 vd = *(const float4*)(vbase + row * 1024 + t0 + (inner >> 1));
            *(float4*)((char*)Ks + wb) = kd;
            *(float4*)((char*)Vs + wb) = vd;
        }
        __syncthreads();

        // QK^T (swapped): lane holds keys 16*sub + 4g + r for q = q16
        f32x4 st[4];
        __builtin_amdgcn_s_setprio(1);
        #pragma unroll
        for (int sub = 0; sub < 4; sub++) {
            #pragma unroll
            for (int r = 0; r < 4; r++) st[sub][r] = 0.f;
            bf16x8 k0 = lds_frag(Ks, sub * 16 + q16, g * 16);
            bf16x8 k1 = lds_frag(Ks, sub * 16 + q16, 64 + g * 16);
            st[sub] = __builtin_amdgcn_mfma_f32_16x16x32_bf16(k0, qf0, st[sub], 0, 0, 0);
            st[sub] = __builtin_amdgcn_mfma_f32_16x16x32_bf16(k1, qf1, st[sub], 0, 0, 0);
        }
        __builtin_amdgcn_s_setprio(0);

        // defer-max (T13): only rescale when some lane's max grew past m+8
        float pmax = -1e30f;
        #pragma unroll
        for (int t = 0; t < 4; t++)
            #pragma unroll
            for (int r = 0; r < 4; r++) pmax = fmaxf(pmax, st[t][r]);
        if (!__all(pmax <= m_cur + 8.f)) {
            float mx = pmax;
            mx = fmaxf(mx, __shfl_xor(mx, 16, 64));
            mx = fmaxf(mx, __shfl_xor(mx, 32, 64));   // per-q16 max over all 64 keys
            float m_new = fmaxf(m_cur, mx);
            float alpha = __expf(m_cur - m_new);
            lsum_part *= alpha;
            #pragma unroll
            for (int r = 0; r < 4; r++) {
                float sc = __shfl(alpha, (g << 2) + r, 64);
                #pragma unroll
                for (int dc = 0; dc < 4; dc++) oacc[dc][r] *= sc;
            }
            m_cur = m_new;
        }

        // P = exp(s - m), lane-local partial sum, pack to bf16
        float psum = 0.f;
        unsigned pk[4][2];
        #pragma unroll
        for (int t = 0; t < 4; t++) {
            float p0 = __expf(st[t][0] - m_cur), p1 = __expf(st[t][1] - m_cur);
            float p2 = __expf(st[t][2] - m_cur), p3 = __expf(st[t][3] - m_cur);
            psum += (p0 + p1) + (p2 + p3);
            pk[t][0] = pack2bf(p0, p1);
            pk[t][1] = pack2bf(p2, p3);
        }
        lsum_part += psum;

        // redistribute P into PV A-fragments
        bool ghi = (g & 2) != 0;
        unsigned pkA0[2], pkA1[2];
        pkA0[0] = ghi ? pk[1][0] : pk[0][0];
        pkA0[1] = ghi ? pk[1][1] : pk[0][1];
        pkA1[0] = ghi ? pk[3][0] : pk[2][0];
        pkA1[1] = ghi ? pk[3][1] : pk[2][1];
        union { int u[4]; bf16x8 v; } A0, A1;
        #pragma unroll
        for (int c = 0; c < 4; c++) {
            int src = (((2 * g + (c >> 1)) & 3) << 4) | q16;
            A0.u[c] = __shfl((int)pkA0[c & 1], src, 64);
            A1.u[c] = __shfl((int)pkA1[c & 1], src, 64);
        }

        __builtin_amdgcn_s_setprio(1);
        #pragma unroll
        for (int dc = 0; dc < 4; dc++) {
            bf16x8 v0 = lds_frag(Vs, dc * 16 + q16, g * 16);
            bf16x8 v1 = lds_frag(Vs, dc * 16 + q16, 64 + g * 16);
            oacc[dc] = __builtin_amdgcn_mfma_f32_16x16x32_bf16(A0.v, v0, oacc[dc], 0, 0, 0);
            oacc[dc] = __builtin_amdgcn_mfma_f32_16x16x32_bf16(A1.v, v1, oacc[dc], 0, 0, 0);
        }
        __builtin_amdgcn_s_setprio(0);
    }

    // final lsum: reduce the 4 g-group partials per q16 (once per kernel)
    lsum_part += __shfl_xor(lsum_part, 16, 64);
    lsum_part += __shfl_xor(lsum_part, 32, 64);
    #pragma unroll
    for (int r = 0; r < 4; r++) {
        float inv = 1.f / __shfl(lsum_part, (g << 2) + r, 64);
        int qrow = (b << 12) + qbase + (g << 2) + r;
        #pragma unroll
        for (int dc = 0; dc < 4; dc++)
            ow[(size_t)qrow * 256 + wh * 64 + dc * 16 + q16] =
                __float2bfloat16(oacc[dc][r] * inv);
    }
}

extern "C" void kernel_launch(void* const* d_in, const int* in_sizes, int n_in,
                              void* d_out, int out_size, void* d_ws, size_t ws_size,
                              hipStream_t stream)
{
    const float* x        = (const float*)d_in[0];
    const float* wq_w     = (const float*)d_in[1];
    const float* kv_ln_g  = (const float*)d_in[2];
    const float* kv_ln_b  = (const float*)d_in[3];
    const float* wkv_w    = (const float*)d_in[4];
    const float* wkv_b    = (const float*)d_in[5];
    const float* wproj_w  = (const float*)d_in[6];
    const float* wproj_b  = (const float*)d_in[7];
    const float* reduce_w = (const float*)d_in[8];
    const float* reduce_b = (const float*)d_in[9];
    const float* rbn_g    = (const float*)d_in[10];
    const float* rbn_b    = (const float*)d_in[11];
    const float* filter_w = (const float*)d_in[12];
    const float* filter_b = (const float*)d_in[13];
    const float* fbn_g    = (const float*)d_in[14];
    const float* fbn_b    = (const float*)d_in[15];
    const float* sqkv_w   = (const float*)d_in[16];
    const float* sproj_w  = (const float*)d_in[17];
    const float* sproj_b  = (const float*)d_in[18];
    float* out = (float*)d_out;
    float* ws  = (float*)d_ws;

    // workspace layout (float units)
    __hip_bfloat16* qkvb  = (__hip_bfloat16*)(ws);             // 12,582,912 bf16
    __hip_bfloat16* owb   = (__hip_bfloat16*)(ws);             // reuse after win_attn
    __hip_bfloat16* sa_ob = (__hip_bfloat16*)(ws + 6291456);   // 4,194,304 bf16
    __hip_bfloat16* xb    = (__hip_bfloat16*)(ws + 8388608);   // 8,388,608 bf16
    __hip_bfloat16* sqkvT = (__hip_bfloat16*)(ws + 12582912);  // 393,216 bf16
    __hip_bfloat16* wqT   = (__hip_bfloat16*)(ws + 12779520);  // 131,072 bf16
    __hip_bfloat16* redT  = (__hip_bfloat16*)(ws + 12845056);  // 32,768 bf16
    __hip_bfloat16* sprojT= (__hip_bfloat16*)(ws + 12861440);  // 65,536 bf16
    __hip_bfloat16* wkvT  = (__hip_bfloat16*)(ws + 12894208);  // 131,072 bf16
    __hip_bfloat16* wprojT= (__hip_bfloat16*)(ws + 13025280);  // 81,920 bf16
    __hip_bfloat16* wt2b  = (__hip_bfloat16*)(ws + 13066240);  // 589,824 bf16
    float* rbuf  = ws + 13361152;                              // 1,048,576 f
    __hip_bfloat16* xd1b  = (__hip_bfloat16*)(ws + 14409728);  // 1,048,576 bf16
    float* xd2   = ws + 14934016;                              // 1,048,576 f
    __hip_bfloat16* kvinb = (__hip_bfloat16*)(ws + 15982592);  // 1,048,576 bf16
    __hip_bfloat16* xidwtb= (__hip_bfloat16*)(ws + 16506880);  // 1,048,576 bf16
    __hip_bfloat16* qbw   = (__hip_bfloat16*)(ws + 17031168);  // 4,194,304 bf16
    __hip_bfloat16* kbb   = (__hip_bfloat16*)(ws + 19128320);  // 1,048,576 bf16
    __hip_bfloat16* vtb   = (__hip_bfloat16*)(ws + 19652608);  // 1,048,576 bf16

    dim3 blk(256);

    // prep: x -> bf16, weight transposes
    cvt_bf16<<<dim3(8192), blk, 0, stream>>>(x, xb);
    wtrans<<<dim3(1536), blk, 0, stream>>>(sqkv_w, sqkvT, 512, 768);
    wtrans<<<dim3(512),  blk, 0, stream>>>(wq_w, wqT, 512, 256);
    wtrans<<<dim3(128),  blk, 0, stream>>>(reduce_w, redT, 512, 64);
    wtrans<<<dim3(256),  blk, 0, stream>>>(sproj_w, sprojT, 256, 256);
    wtrans<<<dim3(512),  blk, 0, stream>>>(wkv_w, wkvT, 256, 512);
    wtrans<<<dim3(320),  blk, 0, stream>>>(wproj_w, wprojT, 320, 256);
    wt_kernel<<<dim3(256), blk, 0, stream>>>(filter_w, wt2b);

    // 1. qkv = xb @ sqkv_w  (bf16 out)
    gemm_bf16<EPI_NONE,1><<<dim3(6,128), blk, 0, stream>>>(xb, 512, sqkvT, 512, qkvb, 768,
                                                           768, nullptr, nullptr, nullptr, 1.f);
    // 2. window attention (bf16 -> bf16)
    win_attn<<<dim3(4096), blk, 0, stream>>>(qkvb, sa_ob);
    // 3. sa_out -> out cols [0,256)
    gemm_bf16<EPI_BIAS,0><<<dim3(2,128), blk, 0, stream>>>(sa_ob, 256, sprojT, 256, out, 512,
                                                           256, sproj_b, nullptr, nullptr, 1.f);
    // 4. qw = (xb @ wq_w) * 0.125 (bf16 out, pre-scaled for flash)
    gemm_bf16<EPI_NONE,1><<<dim3(2,128), blk, 0, stream>>>(xb, 512, wqT, 512, qbw, 256,
                                                           256, nullptr, nullptr, nullptr, WSCALE);
    // 5. r = relu(bn(xb @ reduce_w + b))  (fp32 out, N=64)
    gemm_bf16<EPI_BN_RELU,0><<<dim3(1,128), blk, 0, stream>>>(xb, 512, redT, 512, rbuf, 64,
                                                              64, reduce_b, rbn_g, rbn_b, 1.f);
    // 6. DWT -> bf16
    dwt_kernel<<<dim3(1024), blk, 0, stream>>>(rbuf, xd1b);
    // 7. 3x3 conv MFMA + BN + ReLU -> fp32 xd2
    conv3_mfma<<<dim3(4,64), blk, 0, stream>>>(xd1b, wt2b, xd2, filter_b, fbn_g, fbn_b);
    // 8. layernorm -> bf16
    ln_kernel<<<dim3(4096), blk, 0, stream>>>(xd2, kv_ln_g, kv_ln_b, kvinb);
    // 9. kv GEMM -> bf16 K + transposed V
    gemm_kv_mfma<<<dim3(4,32), blk, 0, stream>>>(kvinb, wkvT, kbb, vtb, wkv_b);
    // 10. IDWT -> bf16
    idwt_kernel<<<dim3(1024), blk, 0, stream>>>(xd2, xidwtb);
    // 11. flash attention -> bf16 ow (reuses qkvb space)
    flash_mfma<<<dim3(64,16), blk, 0, stream>>>(qbw, kbb, vtb, owb);
    // 12. fused wproj: [ow | x_idwt] @ wproj + b -> out cols [256,512)
    gemm_wproj<<<dim3(2,128), blk, 0, stream>>>(owb, xidwtb, wprojT, out + 256, wproj_b);
}